// Round 10
// baseline (1783.189 us; speedup 1.0000x reference)
//
#include <hip/hip_runtime.h>
#include <hip/hip_bf16.h>
#include <stdint.h>
#include <stddef.h>

#define B_  32
#define S_  400
#define T_  32
#define H_  512
#define E_  128
#define V_  50000
#define A_  512
#define H2_ 1024
#define H3_ 1536
#define H4_ 2048
#define R_  1024     // B*T
#define PGK_ 1664    // 3H+E
#define NBLKV_ 391   // ceil(V/128)
#define GRBX_ 128    // X (producer) blocks
#define GRB_  160    // total: 128 X + 32 Y
#define WROW_ 520    // u16 row stride for LDS bf16 tiles (16B-aligned)

typedef unsigned short u16;
typedef short v8s __attribute__((ext_vector_type(8)));
typedef float v4f __attribute__((ext_vector_type(4)));

__device__ __forceinline__ float fsig(float x){ return 1.0f/(1.0f + __expf(-x)); }
__device__ __forceinline__ float ftanh(float x){ float e = __expf(2.0f*x); return 1.0f - 2.0f/(e + 1.0f); }
__device__ __forceinline__ u16 f2bf(float x){ __hip_bfloat16 b = __float2bfloat16(x); return *reinterpret_cast<u16*>(&b); }
__device__ __forceinline__ float bf2f(u16 u){ __hip_bfloat16 b = *reinterpret_cast<__hip_bfloat16*>(&u); return __bfloat162float(b); }

__device__ __forceinline__ float wsum(float v){
  #pragma unroll
  for (int off = 32; off > 0; off >>= 1) v += __shfl_xor(v, off, 64);
  return v;
}
__device__ __forceinline__ float wmax(float v){
  #pragma unroll
  for (int off = 32; off > 0; off >>= 1) v = fmaxf(v, __shfl_xor(v, off, 64));
  return v;
}

#define ALD(p)    __hip_atomic_load((p), __ATOMIC_RELAXED, __HIP_MEMORY_SCOPE_AGENT)
#define AST(p,v)  __hip_atomic_store((p), (v), __ATOMIC_RELAXED, __HIP_MEMORY_SCOPE_AGENT)

// LDS-only barrier: waits lgkmcnt (LDS) but leaves vmem in flight.
__device__ __forceinline__ void ldsbar(){
  asm volatile("s_waitcnt lgkmcnt(0)" ::: "memory");
  __builtin_amdgcn_s_barrier();
  asm volatile("" ::: "memory");
}

// X-producer arrival (call AFTER __syncthreads so all block stores are drained):
// 8 spread group counters (16 arrivals) -> global (8) -> gate := target.
__device__ __forceinline__ void arrive(unsigned* bar, unsigned target, int grp){
  if (threadIdx.x == 0){
    unsigned v = __hip_atomic_fetch_add(bar + grp*32, 1u, __ATOMIC_RELAXED, __HIP_MEMORY_SCOPE_AGENT);
    if (v == target*16u - 1u){
      unsigned g2 = __hip_atomic_fetch_add(bar + 256, 1u, __ATOMIC_RELAXED, __HIP_MEMORY_SCOPE_AGENT);
      if (g2 == target*8u - 1u)
        AST(bar + 288, target);
    }
  }
}
// wait until gate >= target (consumers and producers)
__device__ __forceinline__ void pollgate(unsigned* bar, unsigned target){
  if (threadIdx.x == 0){
    while (ALD(bar + 288) < target) __builtin_amdgcn_s_sleep(2);
    asm volatile("" ::: "memory");
  }
  __syncthreads();
}

// ---------------- setup kernels ----------------

__global__ void k_init0(unsigned* __restrict__ bar){
  int t = threadIdx.x;
  if (t < 512) AST(bar + t, 0u);
}

__global__ __launch_bounds__(256) void k_transpose(const float* __restrict__ in, float* __restrict__ out, int R, int C){
  __shared__ float tile[64][65];
  int c0 = blockIdx.x*64, r0 = blockIdx.y*64;
  int tid = threadIdx.x;
  int cl = tid & 63, q = tid >> 6;
  #pragma unroll
  for (int i=0;i<16;i++){
    int r = q + i*4;
    float v = 0.0f;
    if (r0 + r < R && c0 + cl < C) v = in[(size_t)(r0+r)*C + c0 + cl];
    tile[r][cl] = v;
  }
  __syncthreads();
  #pragma unroll
  for (int i=0;i<16;i++){
    int c = q + i*4;
    if (c0 + c < C && r0 + cl < R)
      out[(size_t)(c0+c)*R + r0 + cl] = tile[cl][c];
  }
}

// f32 [R][C] -> bf16 [C][R] (hi only; used for W_v)
__global__ __launch_bounds__(256) void k_convT(const float* __restrict__ in, u16* __restrict__ hi, int R, int C){
  __shared__ float tile[64][65];
  int c0 = blockIdx.x*64, r0 = blockIdx.y*64;
  int tid = threadIdx.x;
  int cl = tid & 63, q = tid >> 6;
  #pragma unroll
  for (int i=0;i<16;i++){
    int r = q + i*4;
    float v = 0.0f;
    if (r0 + r < R && c0 + cl < C) v = in[(size_t)(r0+r)*C + c0 + cl];
    tile[r][cl] = v;
  }
  __syncthreads();
  #pragma unroll
  for (int i=0;i<16;i++){
    int c = q + i*4;
    if (c0 + c < C && r0 + cl < R)
      hi[(size_t)(c0+c)*R + r0 + cl] = f2bf(tile[cl][c]);
  }
}

// W_enc [1024][512] f32 -> WencT3 [512][3072] bf16 rows = [hi | lo | hi]
__global__ __launch_bounds__(256) void k_convT3(const float* __restrict__ in, u16* __restrict__ out){
  __shared__ float tile[64][65];
  int c0 = blockIdx.x*64, r0 = blockIdx.y*64;   // grid (8,16)
  int tid = threadIdx.x;
  int cl = tid & 63, q = tid >> 6;
  #pragma unroll
  for (int i=0;i<16;i++){
    int r = q + i*4;
    tile[r][cl] = in[(size_t)(r0+r)*A_ + c0 + cl];
  }
  __syncthreads();
  #pragma unroll
  for (int i=0;i<16;i++){
    int c = q + i*4;
    float v = tile[cl][c];
    u16 h = f2bf(v);
    u16 lo = f2bf(v - bf2f(h));
    size_t o = (size_t)(c0+c)*3072 + (r0+cl);
    out[o] = h;
    out[o + 1024] = lo;
    out[o + 2048] = h;
  }
}

// enc [12800][1024] f32 -> enc3 [12800][3072] bf16 rows = [hi | hi | lo]
__global__ void k_conv3(const float* __restrict__ in, u16* __restrict__ out, int n4){
  int i = blockIdx.x*256 + threadIdx.x;
  if (i >= n4) return;
  float4 x = reinterpret_cast<const float4*>(in)[i];
  u16 h0v=f2bf(x.x), h1v=f2bf(x.y), h2v=f2bf(x.z), h3v=f2bf(x.w);
  uint2 hv; hv.x = (unsigned)h0v | ((unsigned)h1v << 16); hv.y = (unsigned)h2v | ((unsigned)h3v << 16);
  uint2 lv;
  lv.x = (unsigned)f2bf(x.x - bf2f(h0v)) | ((unsigned)f2bf(x.y - bf2f(h1v)) << 16);
  lv.y = (unsigned)f2bf(x.z - bf2f(h2v)) | ((unsigned)f2bf(x.w - bf2f(h3v)) << 16);
  int row = i >> 8, c = (i & 255)*4;
  size_t base = (size_t)row*3072 + c;
  *reinterpret_cast<uint2*>(out + base)        = hv;
  *reinterpret_cast<uint2*>(out + base + 1024) = hv;
  *reinterpret_cast<uint2*>(out + base + 2048) = lv;
}

// G2[t][g][hidx][b] = b_ih + b_hh + emb @ W_ih^T   (layout for k_recur coalesced reads)
__global__ __launch_bounds__(256) void k_gih(const float* __restrict__ emb, const float* __restrict__ WihT,
    const float* __restrict__ b_ih, const float* __restrict__ b_hh, float* __restrict__ G){
  __shared__ float em[8][128];
  int r0 = blockIdx.x*8;
  int tid = threadIdx.x;
  #pragma unroll
  for (int i=0;i<4;i++){
    int e = i*256 + tid;
    em[e>>7][e&127] = emb[(size_t)(r0 + (e>>7))*E_ + (e&127)];
  }
  __syncthreads();
  for (int jj=0;jj<8;jj++){
    int j = jj*256 + tid;
    float bias = b_ih[j] + b_hh[j];
    float acc[8];
    #pragma unroll
    for (int r=0;r<8;r++) acc[r] = bias;
    for (int e=0;e<128;e++){
      float wv = WihT[(size_t)e*H4_ + j];
      #pragma unroll
      for (int r=0;r<8;r++) acc[r] += em[r][e]*wv;
    }
    #pragma unroll
    for (int rr=0;rr<8;rr++){
      int r = r0 + rr;
      G[(size_t)(r & 31)*65536 + (size_t)(j >> 9)*16384 + (size_t)(j & 511)*32 + (r >> 5)] = acc[rr];
    }
  }
}

// ---------------- MFMA bf16 GEMM (coalesced LDS epilogue, optional stats) ----------------
__global__ __launch_bounds__(256, 2) void k_gemm_bf16(
    const u16* __restrict__ A, int lda, const u16* __restrict__ Bt, int ldb,
    const float* __restrict__ bias, float* __restrict__ Cf, u16* __restrict__ Cbf, int ldc,
    int M, int N, int K, float2* __restrict__ stats, int nblk)
{
  __shared__ __align__(16) float CsF[128*132];
  __shared__ float rs[128], rs2[128];
  u16* As = reinterpret_cast<u16*>(CsF);
  u16* Bs = As + 128*64;
  const int tid = threadIdx.x;
  const int m0 = blockIdx.y * 128;
  const int n0 = blockIdx.x * 128;
  const int l  = tid & 63;
  const int wavebase = tid & ~63;
  const int wid = tid >> 6;
  const int wm = (wid >> 1) * 64;
  const int wn = (wid & 1) * 64;

  v4f acc[4][4];
  v4f vzero = {0.0f, 0.0f, 0.0f, 0.0f};
  #pragma unroll
  for (int i=0;i<4;i++)
    #pragma unroll
    for (int j=0;j<4;j++) acc[i][j] = vzero;

  for (int k0 = 0; k0 < K; k0 += 64){
    __syncthreads();
    #pragma unroll
    for (int jj=0;jj<4;jj++){
      int fc = jj*256 + tid;
      int row = fc >> 3;
      int cc = (fc & 7) ^ (row & 7);
      const u16* g = A + (size_t)(m0 + row)*lda + k0 + cc*8;
      __builtin_amdgcn_global_load_lds(
        (__attribute__((address_space(1))) void*)g,
        (__attribute__((address_space(3))) void*)(As + (size_t)(jj*256 + wavebase)*8),
        16, 0, 0);
    }
    #pragma unroll
    for (int jj=0;jj<4;jj++){
      int fc = jj*256 + tid;
      int row = fc >> 3;
      int cc = (fc & 7) ^ (row & 7);
      int rn = n0 + row; if (rn > N-1) rn = N-1;
      const u16* g = Bt + (size_t)rn*ldb + k0 + cc*8;
      __builtin_amdgcn_global_load_lds(
        (__attribute__((address_space(1))) void*)g,
        (__attribute__((address_space(3))) void*)(Bs + (size_t)(jj*256 + wavebase)*8),
        16, 0, 0);
    }
    __syncthreads();
    #pragma unroll
    for (int ks=0;ks<2;ks++){
      v8s af[4], bfr[4];
      #pragma unroll
      for (int rt=0;rt<4;rt++){
        int r = wm + rt*16 + (l & 15);
        int cs = (ks*4 + (l >> 4)) ^ (r & 7);
        af[rt] = *reinterpret_cast<const v8s*>(As + r*64 + cs*8);
      }
      #pragma unroll
      for (int nt=0;nt<4;nt++){
        int r = wn + nt*16 + (l & 15);
        int cs = (ks*4 + (l >> 4)) ^ (r & 7);
        bfr[nt] = *reinterpret_cast<const v8s*>(Bs + r*64 + cs*8);
      }
      #pragma unroll
      for (int rt=0;rt<4;rt++)
        #pragma unroll
        for (int nt=0;nt<4;nt++)
          acc[rt][nt] = __builtin_amdgcn_mfma_f32_16x16x32_bf16(af[rt], bfr[nt], acc[rt][nt], 0, 0, 0);
    }
  }

  const int cl = l & 15;
  const int rg = (l >> 4) * 4;
  float cvv[4][4][4];
  #pragma unroll
  for (int rt=0;rt<4;rt++)
    #pragma unroll
    for (int nt=0;nt<4;nt++){
      int gc = n0 + wn + nt*16 + cl;
      float bv = (bias && gc < N) ? bias[gc] : 0.0f;
      #pragma unroll
      for (int i=0;i<4;i++) cvv[rt][nt][i] = acc[rt][nt][i] + bv;
    }

  if (stats){
    float tsm[4][4];
    #pragma unroll
    for (int rt=0;rt<4;rt++)
      #pragma unroll
      for (int i=0;i<4;i++){
        float mx = -1e30f;
        #pragma unroll
        for (int nt=0;nt<4;nt++){
          int gc = n0 + wn + nt*16 + cl;
          if (gc < N) mx = fmaxf(mx, cvv[rt][nt][i]);
        }
        #pragma unroll
        for (int off=1; off<16; off<<=1) mx = fmaxf(mx, __shfl_xor(mx, off, 64));
        if (wn == 0 && cl == 0) rs[wm + rt*16 + rg + i] = mx;
        tsm[rt][i] = mx;
      }
    __syncthreads();
    if (wn != 0){
      #pragma unroll
      for (int rt=0;rt<4;rt++)
        #pragma unroll
        for (int i=0;i<4;i++){
          float c = fmaxf(tsm[rt][i], rs[wm + rt*16 + rg + i]);
          if (cl == 0) rs[wm + rt*16 + rg + i] = c;
        }
    }
    __syncthreads();
    #pragma unroll
    for (int rt=0;rt<4;rt++)
      #pragma unroll
      for (int i=0;i<4;i++){
        float rm = rs[wm + rt*16 + rg + i];
        float sm = 0.0f;
        #pragma unroll
        for (int nt=0;nt<4;nt++){
          int gc = n0 + wn + nt*16 + cl;
          if (gc < N) sm += __expf(cvv[rt][nt][i] - rm);
        }
        #pragma unroll
        for (int off=1; off<16; off<<=1) sm += __shfl_xor(sm, off, 64);
        tsm[rt][i] = sm;
        if (wn == 0 && cl == 0) rs2[wm + rt*16 + rg + i] = sm;
      }
    __syncthreads();
    if (wn != 0 && cl == 0){
      #pragma unroll
      for (int rt=0;rt<4;rt++)
        #pragma unroll
        for (int i=0;i<4;i++){
          int row = wm + rt*16 + rg + i;
          stats[(size_t)(m0 + row)*nblk + blockIdx.x] =
            make_float2(rs[row], tsm[rt][i] + rs2[row]);
        }
    }
  }

  __syncthreads();
  #pragma unroll
  for (int rt=0;rt<4;rt++)
    #pragma unroll
    for (int nt=0;nt<4;nt++)
      #pragma unroll
      for (int i=0;i<4;i++)
        CsF[(wm + rt*16 + rg + i)*132 + wn + nt*16 + cl] = cvv[rt][nt][i];
  __syncthreads();
  #pragma unroll
  for (int it=0; it<16; ++it){
    int row = (tid >> 5) + it*8;
    int c4 = tid & 31;
    int gc = n0 + c4*4;
    int gr = m0 + row;
    if (gc < N){
      float4 v = *reinterpret_cast<const float4*>(&CsF[row*132 + c4*4]);
      if (Cf) *reinterpret_cast<float4*>(Cf + (size_t)gr*ldc + gc) = v;
      if (Cbf){
        uint2 o;
        o.x = (unsigned)f2bf(v.x) | ((unsigned)f2bf(v.y) << 16);
        o.y = (unsigned)f2bf(v.z) | ((unsigned)f2bf(v.w) << 16);
        *reinterpret_cast<uint2*>(Cbf + (size_t)gr*ldc + gc) = o;
      }
    }
  }
}

// fallback f32 GEMM for W_v when ws too small
__global__ __launch_bounds__(256) void k_wv_f32(
  const float* __restrict__ Aah, const float* __restrict__ Wv, const float* __restrict__ bv,
  float* __restrict__ Cl)
{
  __shared__ float Asf[32][68];
  __shared__ float Bsf[32][64];
  int n0 = blockIdx.x*64, m0 = blockIdx.y*64;
  int tid = threadIdx.x;
  int tx = tid & 15, ty = tid >> 4;
  float acc[4][4] = {};
  for (int kc = 0; kc < H_; kc += 32){
    __syncthreads();
    #pragma unroll
    for (int i=0;i<8;i++){
      int e = i*256 + tid;
      Asf[e & 31][e >> 5] = Aah[(size_t)(m0 + (e >> 5))*H_ + kc + (e & 31)];
    }
    #pragma unroll
    for (int i=0;i<8;i++){
      int e = i*256 + tid;
      int nc = n0 + (e & 63); if (nc >= V_) nc = V_-1;
      Bsf[e >> 6][e & 63] = Wv[(size_t)(kc + (e >> 6))*V_ + nc];
    }
    __syncthreads();
    #pragma unroll
    for (int k=0;k<32;k++){
      float4 a4 = *reinterpret_cast<const float4*>(&Asf[k][ty*4]);
      float4 b4 = *reinterpret_cast<const float4*>(&Bsf[k][tx*4]);
      float av[4] = {a4.x, a4.y, a4.z, a4.w};
      float bv4[4] = {b4.x, b4.y, b4.z, b4.w};
      #pragma unroll
      for (int i=0;i<4;i++)
        #pragma unroll
        for (int j=0;j<4;j++)
          acc[i][j] = __builtin_fmaf(av[i], bv4[j], acc[i][j]);
    }
  }
  #pragma unroll
  for (int i=0;i<4;i++){
    int rr = m0 + ty*4 + i;
    #pragma unroll
    for (int j=0;j<4;j++){
      int cc = n0 + tx*4 + j;
      if (cc < V_) Cl[(size_t)rr*V_ + cc] = acc[i][j] + bv[cc];
    }
  }
}

// ---------------- persistent recurrence: producer/consumer split ----------------
// X blocks (0..127): per iter i: poll gate>=i; stage h_i; MFMA gates_i + dec_{i-1}
//   (published to step-indexed dec_steps); LSTM -> h_steps[i+1]; arrive(i+1).
//   X never waits on Y (step-indexed buffers, never overwritten).
// Y blocks (128..159, one per batch): per step s: poll gate>=s+2; read dec_steps[s];
//   compute ALL 400 scores locally; block softmax; attn/cov. No exchanges.
__global__ __launch_bounds__(1024) void k_recur(
  const float* __restrict__ W_hh, const float* __restrict__ G2,
  const float* __restrict__ W_decT, const u16* __restrict__ ep_bf,
  const float* __restrict__ w_cov, const float* __restrict__ v_att,
  const void* __restrict__ maskp, const float* __restrict__ h0,
  const float* __restrict__ c0, float* __restrict__ h_steps,
  float* __restrict__ dec_steps,
  float* __restrict__ catbuf, float* __restrict__ attns, float* __restrict__ covs,
  unsigned* __restrict__ bar)
{
  const int beta = blockIdx.x;
  const int tid = threadIdx.x;
  __shared__ __align__(16) u16 Whi[32*WROW_];   // X: rows 16 gate, 4 dec, 12 zero
  __shared__ __align__(16) u16 Wlo[32*WROW_];
  __shared__ __align__(16) u16 Hhi[32*WROW_];   // X: [b][k] bf16
  __shared__ __align__(16) u16 Hlo[32*WROW_];
  __shared__ float gv2[16][32];                 // X: reduced gates
  __shared__ float c_l[128];                    // X
  __shared__ float dec_l[512];                  // Y
  __shared__ float sc_l[400];                   // Y
  __shared__ float cov_l[400];                  // Y
  __shared__ float red[16];                     // Y

  const int b32 = tid & 31;
  const int w = tid >> 6, l = tid & 63;

  if (beta < GRBX_){
    // =================== X: producer ===================
    const int grp = beta & 7;
    const int b2 = (tid & 15)*2;
    const int kg = tid >> 4;

    // one-time: W rows (16 gates + 4 dec + 12 zero) as bf16 hi/lo
    for (int idx = tid; idx < 32*512; idx += 1024){
      int row = idx >> 9;
      int k = idx & 511;
      float v = 0.0f;
      if (row < 16)      v = W_hh[((size_t)(row >> 2)*H_ + beta*4 + (row & 3))*H_ + k];
      else if (row < 20) v = W_decT[(size_t)(beta*4 + (row - 16))*H_ + k];
      u16 h = f2bf(v);
      Whi[row*WROW_ + k] = h;
      Wlo[row*WROW_ + k] = f2bf(v - bf2f(h));
    }
    if (tid < 128) c_l[tid] = c0[(size_t)(tid & 31)*H_ + beta*4 + (tid >> 5)];

    float hA[8], hB[8];
    #pragma unroll
    for (int kk=0;kk<8;kk++){
      int k = kg*8 + kk;
      hA[kk] = h0[(size_t)b2*H_ + k];
      hB[kk] = h0[(size_t)(b2+1)*H_ + k];
    }
    __syncthreads();

    for (int i = 0; i <= T_; ++i){
      if (i > 0){
        pollgate(bar, (unsigned)i);
        unsigned long long hld[8];
        const unsigned long long* hp =
          reinterpret_cast<const unsigned long long*>(h_steps + (size_t)i*16384);
        #pragma unroll
        for (int kk=0;kk<8;kk++)
          hld[kk] = ALD(hp + (size_t)(kg*8 + kk)*16 + (b2 >> 1));
        #pragma unroll
        for (int kk=0;kk<8;kk++){
          hA[kk] = __uint_as_float((unsigned)hld[kk]);
          hB[kk] = __uint_as_float((unsigned)(hld[kk] >> 32));
        }
      }
      // cvt h -> bf16 hi/lo [b][k]
      {
        v8s phA, plA, phB, plB;
        #pragma unroll
        for (int kk=0;kk<8;kk++){
          float va = hA[kk], vb = hB[kk];
          u16 ha = f2bf(va), hb = f2bf(vb);
          phA[kk] = (short)ha; plA[kk] = (short)f2bf(va - bf2f(ha));
          phB[kk] = (short)hb; plB[kk] = (short)f2bf(vb - bf2f(hb));
        }
        *reinterpret_cast<v8s*>(Hhi + (size_t)b2*WROW_ + kg*8) = phA;
        *reinterpret_cast<v8s*>(Hlo + (size_t)b2*WROW_ + kg*8) = plA;
        *reinterpret_cast<v8s*>(Hhi + (size_t)(b2+1)*WROW_ + kg*8) = phB;
        *reinterpret_cast<v8s*>(Hlo + (size_t)(b2+1)*WROW_ + kg*8) = plB;
      }
      ldsbar();

      // MFMA gates+dec: D[20x32] = W · h^T, split-bf16 3 passes
      if (w < 4){
        const int mt = w >> 1, nt = w & 1;
        const int fr = (l & 15);
        const int fo = (l >> 4)*8;
        const u16* Ahi = Whi + (size_t)(mt*16 + fr)*WROW_ + fo;
        const u16* Alo = Wlo + (size_t)(mt*16 + fr)*WROW_ + fo;
        const u16* Bhi = Hhi + (size_t)(nt*16 + fr)*WROW_ + fo;
        const u16* Blo = Hlo + (size_t)(nt*16 + fr)*WROW_ + fo;
        v4f a0 = {0.f,0.f,0.f,0.f}, a1 = a0, a2 = a0;
        #pragma unroll
        for (int ks=0; ks<16; ks++){
          v8s wh = *reinterpret_cast<const v8s*>(Ahi + ks*32);
          v8s wl = *reinterpret_cast<const v8s*>(Alo + ks*32);
          v8s hh = *reinterpret_cast<const v8s*>(Bhi + ks*32);
          v8s hl = *reinterpret_cast<const v8s*>(Blo + ks*32);
          a0 = __builtin_amdgcn_mfma_f32_16x16x32_bf16(wh, hh, a0, 0, 0, 0);
          a1 = __builtin_amdgcn_mfma_f32_16x16x32_bf16(wh, hl, a1, 0, 0, 0);
          a2 = __builtin_amdgcn_mfma_f32_16x16x32_bf16(wl, hh, a2, 0, 0, 0);
        }
        v4f acc = a0 + a1 + a2;
        if (mt == 0){
          int col = nt*16 + fr;
          int r0w = (l >> 4)*4;
          #pragma unroll
          for (int q=0;q<4;q++) gv2[r0w + q][col] = acc[q];
        } else if ((l >> 4) == 0 && i > 0){
          int b = nt*16 + fr;
          float* dg = dec_steps + (size_t)(i-1)*B_*A_ + (size_t)b*A_ + beta*4;
          unsigned long long p0 = ((unsigned long long)__float_as_uint(acc[1]) << 32) | __float_as_uint(acc[0]);
          unsigned long long p1 = ((unsigned long long)__float_as_uint(acc[3]) << 32) | __float_as_uint(acc[2]);
          AST(reinterpret_cast<unsigned long long*>(dg), p0);
          AST(reinterpret_cast<unsigned long long*>(dg + 2), p1);
        }
      }
      ldsbar();

      // LSTM pointwise + publish h_{i+1}
      if (i < T_ && tid < 128){
        int hh = tid >> 5;
        int hidx = beta*4 + hh;
        const float* Gr = G2 + (size_t)i*65536 + (size_t)hidx*32 + b32;
        float gi = gv2[0*4+hh][b32] + Gr[0];
        float gf = gv2[1*4+hh][b32] + Gr[16384];
        float gz = gv2[2*4+hh][b32] + Gr[32768];
        float go = gv2[3*4+hh][b32] + Gr[49152];
        float co = c_l[tid];
        float cn = fsig(gf)*co + fsig(gi)*ftanh(gz);
        float hn = fsig(go)*ftanh(cn);
        c_l[tid] = cn;
        AST(h_steps + (size_t)(i+1)*16384 + (size_t)hidx*32 + b32, hn);
        catbuf[(size_t)(b32*T_ + i)*H3_ + H2_ + hidx] = hn;
      }
      __syncthreads();          // drain all publishes (vmcnt) before arrival
      arrive(bar, (unsigned)(i+1), grp);
    }
  } else {
    // =================== Y: consumer (one batch per block) ===================
    const int bb = beta - GRBX_;
    if (tid < 400) cov_l[tid] = 0.f;

    const unsigned* m32p = (const unsigned*)maskp;
    const unsigned char* m8p = (const unsigned char*)maskp;
    const bool bytemode = (m32p[0] == 0x01010101u);

    float wc8[8], va8[8];
    {
      int a0 = l*8;
      #pragma unroll
      for (int j=0;j<8;j++){ wc8[j] = w_cov[a0+j]; va8[j] = v_att[a0+j]; }
    }
    __syncthreads();

    for (int s = 0; s < T_; ++s){
      pollgate(bar, (unsigned)(s + 2));
      // read dec_steps[s][bb] (coherent)
      if (tid < 256){
        unsigned long long v = ALD(reinterpret_cast<const unsigned long long*>(
            dec_steps + (size_t)s*B_*A_ + (size_t)bb*A_) + tid);
        dec_l[tid*2]   = __uint_as_float((unsigned)v);
        dec_l[tid*2+1] = __uint_as_float((unsigned)(v >> 32));
      }
      ldsbar();
      int a0i = l*8;
      float dec8[8];
      #pragma unroll
      for (int j=0;j<8;j++) dec8[j] = dec_l[a0i+j];
      #pragma unroll 5
      for (int it=0; it<25; ++it){
        int sl = w + it*16;       // 16 warps x 25 = 400, all < 400
        float cv = cov_l[sl];
        uint4 e8 = *reinterpret_cast<const uint4*>(ep_bf + (size_t)(bb*S_ + sl)*A_ + a0i);
        unsigned uu[4] = {e8.x, e8.y, e8.z, e8.w};
        float part = 0.f;
        #pragma unroll
        for (int j=0;j<4;j++){
          float xa = bf2f((u16)(uu[j] & 0xFFFFu)) + dec8[2*j]   + cv*wc8[2*j];
          part += va8[2*j]*ftanh(xa);
          float xb = bf2f((u16)(uu[j] >> 16))     + dec8[2*j+1] + cv*wc8[2*j+1];
          part += va8[2*j+1]*ftanh(xb);
        }
        part = wsum(part);
        if (l == 0){
          bool on = bytemode ? (m8p[bb*S_+sl] != 0) : (m32p[bb*S_+sl] != 0u);
          sc_l[sl] = on ? part : -1e9f;
        }
      }
      __syncthreads();
      // block softmax over 400
      float x = (tid < 400) ? sc_l[tid] : -1e30f;
      if (w < 7){
        float m = wmax(x);
        if (l == 0) red[w] = m;
      }
      __syncthreads();
      float gm = red[0];
      #pragma unroll
      for (int j=1;j<7;j++) gm = fmaxf(gm, red[j]);
      float z = (tid < 400) ? __expf(x - gm) : 0.f;
      if (w < 7){
        float zs = wsum(z);
        if (l == 0) red[8 + w] = zs;
      }
      __syncthreads();
      float gZ = red[8];
      #pragma unroll
      for (int j=9;j<15;j++) gZ += red[j];
      float invZ = 1.f/gZ;
      int r = bb*T_ + s;
      if (tid < 400){
        float av = z*invZ;
        float cn = cov_l[tid] + av;
        cov_l[tid] = cn;
        attns[(size_t)r*S_ + tid] = av;
        covs[(size_t)r*S_ + tid]  = cn;
      }
      __syncthreads();
    }
  }
}

// ---------------- post-loop kernels ----------------

// context (deferred): catbuf[:, :1024] = attns @ enc   (fp32, single enc pass)
__global__ __launch_bounds__(256, 2) void k_ctx(
  const float* __restrict__ attns, const float* __restrict__ enc, float* __restrict__ catbuf)
{
  __shared__ float att_s[32][400];
  int d0 = blockIdx.x*64, b = blockIdx.y;
  int tid = threadIdx.x;
  for (int tt=0; tt<32; ++tt)
    for (int s = tid; s < S_; s += 256)
      att_s[tt][s] = attns[(size_t)(b*T_ + tt)*S_ + s];
  __syncthreads();
  int d = d0 + (tid & 63);
  int t0 = (tid >> 6)*8;
  float acc[8] = {0,0,0,0,0,0,0,0};
  const float* encb = enc + (size_t)b*S_*H2_ + d;
  #pragma unroll 4
  for (int s=0; s<S_; ++s){
    float ev = encb[(size_t)s*H2_];
    #pragma unroll
    for (int i=0;i<8;i++) acc[i] = __builtin_fmaf(att_s[t0+i][s], ev, acc[i]);
  }
  #pragma unroll
  for (int i=0;i<8;i++)
    catbuf[(size_t)(b*T_ + t0 + i)*H3_ + d] = acc[i];
}

// fp32 tiled GEMM: dec_states = tanh(catbuf @ W_ah + b_ah); optional bf16 copy
__global__ __launch_bounds__(256) void k_ahgemm(
  const float* __restrict__ Acat, const float* __restrict__ W_ah, const float* __restrict__ b_ah,
  float* __restrict__ dec_states, u16* __restrict__ ah_bf)
{
  __shared__ float Asf[32][68];
  __shared__ float Bsf[32][64];
  int n0 = blockIdx.x*64, m0 = blockIdx.y*64;
  int tid = threadIdx.x;
  int tx = tid & 15, ty = tid >> 4;
  float acc[4][4] = {};
  for (int kc = 0; kc < H3_; kc += 32){
    __syncthreads();
    #pragma unroll
    for (int i=0;i<8;i++){
      int e = i*256 + tid;
      Asf[e & 31][e >> 5] = Acat[(size_t)(m0 + (e >> 5))*H3_ + kc + (e & 31)];
    }
    #pragma unroll
    for (int i=0;i<8;i++){
      int e = i*256 + tid;
      Bsf[e >> 6][e & 63] = W_ah[(size_t)(kc + (e >> 6))*H_ + n0 + (e & 63)];
    }
    __syncthreads();
    #pragma unroll
    for (int k=0;k<32;k++){
      float4 a4 = *reinterpret_cast<const float4*>(&Asf[k][ty*4]);
      float4 b4 = *reinterpret_cast<const float4*>(&Bsf[k][tx*4]);
      float av[4] = {a4.x, a4.y, a4.z, a4.w};
      float bv[4] = {b4.x, b4.y, b4.z, b4.w};
      #pragma unroll
      for (int i=0;i<4;i++)
        #pragma unroll
        for (int j=0;j<4;j++)
          acc[i][j] = __builtin_fmaf(av[i], bv[j], acc[i][j]);
    }
  }
  #pragma unroll
  for (int i=0;i<4;i++){
    int rr = m0 + ty*4 + i;
    #pragma unroll
    for (int j=0;j<4;j++){
      int cc = n0 + tx*4 + j;
      float v = ftanh(acc[i][j] + b_ah[cc]);
      dec_states[(size_t)rr*H_ + cc] = v;
      if (ah_bf) ah_bf[(size_t)rr*H_ + cc] = f2bf(v);
    }
  }
}

__global__ __launch_bounds__(512) void k_pgen(const float* __restrict__ catbuf, const float* __restrict__ emb,
  const float* __restrict__ W_pg, const float* __restrict__ b_pg, float* __restrict__ pgens)
{
  int w = threadIdx.x >> 6, l = threadIdx.x & 63;
  int r = blockIdx.x*8 + w;
  float part = 0.0f;
  for (int d = l; d < PGK_; d += 64){
    float x = (d < H3_) ? catbuf[(size_t)r*H3_ + d] : emb[(size_t)r*E_ + (d - H3_)];
    part += x*W_pg[d];
  }
  part = wsum(part);
  if (l == 0) pgens[r] = fsig(part + b_pg[0]);
}

// per-row final: stats merge -> bitmask+hash scatter -> fast log transform
__global__ __launch_bounds__(512) void k_final2(
  float* __restrict__ logits, const float* __restrict__ pgens,
  const float* __restrict__ attns, const int* __restrict__ src,
  const float2* __restrict__ stats, int nblk)
{
  __shared__ unsigned bits[1568];
  __shared__ unsigned keys[1024];
  __shared__ float vals[1024];
  __shared__ float sred[18];
  int r = blockIdx.x;
  int b = r >> 5;
  int tid = threadIdx.x;
  int w = tid >> 6, l = tid & 63;
  float* row = logits + (size_t)r*V_;

  for (int i = tid; i < 1568; i += 512) bits[i] = 0u;
  for (int i = tid; i < 1024; i += 512){ keys[i] = 0xFFFFFFFFu; vals[i] = 0.0f; }

  if (stats){
    float m = -1e30f, Z = 0.0f;
    if (tid < nblk){ float2 st = stats[(size_t)r*nblk + tid]; m = st.x; Z = st.y; }
    #pragma unroll
    for (int off=32; off>0; off>>=1){
      float mo = __shfl_xor(m, off, 64);
      float Zo = __shfl_xor(Z, off, 64);
      float nm = fmaxf(m, mo);
      Z = Z*__expf(m - nm) + Zo*__expf(mo - nm);
      m = nm;
    }
    if (l == 0){ sred[w*2] = m; sred[w*2+1] = Z; }
    __syncthreads();
    if (tid == 0){
      float gm = -1e30f, gz = 0.0f;
      #pragma unroll
      for (int i=0;i<8;i++){
        float mi = sred[i*2], zi = sred[i*2+1];
        float nm = fmaxf(gm, mi);
        gz = gz*__expf(gm - nm) + zi*__expf(mi - nm);
        gm = nm;
      }
      sred[16] = gm; sred[17] = gz;
    }
    __syncthreads();
  } else {
    float m = -1e30f;
    for (int j = tid; j < V_/4; j += 512){
      float4 x = reinterpret_cast<const float4*>(row)[j];
      m = fmaxf(fmaxf(m, x.x), fmaxf(fmaxf(x.y, x.z), x.w));
    }
    m = wmax(m);
    if (l == 0) sred[w] = m;
    __syncthreads();
    if (tid == 0){
      float gm = -1e30f;
      #pragma unroll
      for (int i=0;i<8;i++) gm = fmaxf(gm, sred[i]);
      sred[16] = gm;
    }
    __syncthreads();
    float gm = sred[16];
    float z = 0.0f;
    for (int j = tid; j < V_/4; j += 512){
      float4 x = reinterpret_cast<const float4*>(row)[j];
      z += __expf(x.x-gm) + __expf(x.y-gm) + __expf(x.z-gm) + __expf(x.w-gm);
    }
    z = wsum(z);
    if (l == 0) sred[8 + w] = z;
    __syncthreads();
    if (tid == 0){
      float gz = 0.0f;
      #pragma unroll
      for (int i=0;i<8;i++) gz += sred[8 + i];
      sred[17] = gz;
    }
    __syncthreads();
  }

  float gm = sred[16];
  float gZ = sred[17];
  float pg = pgens[r];
  float scale = pg / gZ;
  float lscale = __logf(scale);

  if (tid < S_){
    int tok = src[b*S_ + tid];
    float add = (1.0f - pg)*attns[(size_t)r*S_ + tid];
    atomicOr(&bits[tok >> 5], 1u << (tok & 31));
    unsigned h = ((unsigned)tok * 2654435761u) >> 22;
    while (true){
      unsigned prev = atomicCAS(&keys[h], 0xFFFFFFFFu, (unsigned)tok);
      if (prev == 0xFFFFFFFFu || prev == (unsigned)tok){
        atomicAdd(&vals[h], add);
        break;
      }
      h = (h + 1) & 1023;
    }
  }
  __syncthreads();

  for (int j = tid; j < V_/4; j += 512){
    float4 x = reinterpret_cast<const float4*>(row)[j];
    int v = 4*j;
    float o[4];
    float xv[4] = {x.x, x.y, x.z, x.w};
    #pragma unroll
    for (int k=0;k<4;k++){
      int vv = v + k;
      bool hit = (bits[vv >> 5] >> (vv & 31)) & 1u;
      float tt = xv[k] - gm + lscale;
      if (!hit && tt > -25.0f){
        o[k] = tt;
      } else {
        float pval = __expf(xv[k] - gm)*scale;
        if (hit){
          unsigned h = ((unsigned)vv * 2654435761u) >> 22;
          while (keys[h] != 0xFFFFFFFFu){
            if (keys[h] == (unsigned)vv){ pval += vals[h]; break; }
            h = (h + 1) & 1023;
          }
        }
        o[k] = __logf(pval + 1e-20f);
      }
    }
    reinterpret_cast<float4*>(row)[j] = make_float4(o[0], o[1], o[2], o[3]);
  }
}

// ---------------- host ----------------

extern "C" void kernel_launch(void* const* d_in, const int* in_sizes, int n_in,
                              void* d_out, int out_size, void* d_ws, size_t ws_size,
                              hipStream_t stream)
{
  const int* src_tokens = (const int*)d_in[0];
  const float* embedded = (const float*)d_in[1];
  const float* enc      = (const float*)d_in[2];
  const void*  maskp    = (const void*)d_in[3];
  const float* h0  = (const float*)d_in[4];
  const float* c0  = (const float*)d_in[5];
  const float* W_ih = (const float*)d_in[6];
  const float* W_hh = (const float*)d_in[7];
  const float* b_ih = (const float*)d_in[8];
  const float* b_hh = (const float*)d_in[9];
  const float* W_enc = (const float*)d_in[10];
  const float* W_dec = (const float*)d_in[11];
  const float* w_cov = (const float*)d_in[12];
  const float* b_att = (const float*)d_in[13];
  const float* v_att = (const float*)d_in[14];
  const float* W_ah  = (const float*)d_in[15];
  const float* b_ah  = (const float*)d_in[16];
  const float* W_pg  = (const float*)d_in[17];
  const float* b_pg  = (const float*)d_in[18];
  const float* W_v   = (const float*)d_in[19];
  const float* b_v   = (const float*)d_in[20];
  (void)in_sizes; (void)n_in; (void)out_size;

  float* outp = (float*)d_out;
  float* logps = outp;                                  // (B,T,V)   204.8 MB
  float* dec_states = logps + (size_t)R_*V_;            // (B,T,H)
  float* attns = dec_states + (size_t)R_*H_;            // (B,T,S)
  float* covs  = attns + (size_t)R_*S_;                 // (B,T,S)
  float* pgens = covs + (size_t)R_*S_;                  // (B,T)

  // big transients live INSIDE the logps output region (dead until W_v GEMM)
  char* sp = (char*)logps;
  auto salloc = [&](size_t bytes) -> void* {
    void* p = (void*)sp;
    sp += (bytes + 255) & ~(size_t)255;
    return p;
  };
  unsigned* bar = (unsigned*)salloc(2048);
  u16* ep_bf    = (u16*)salloc((size_t)B_*S_*A_*2);        // 13.1 MB
  u16* enc3     = (u16*)salloc((size_t)B_*S_*3072*2);      // 78.6 MB
  u16* WencT3   = (u16*)salloc((size_t)A_*3072*2);         // 3.1 MB
  float* WihT   = (float*)salloc((size_t)E_*H4_*4);        // 1 MB
  float* W_decT = (float*)salloc((size_t)H_*A_*4);         // 1 MB
  float* G2     = (float*)salloc((size_t)R_*H4_*4);        // 8.4 MB [t][g][hidx][b]
  float* catbuf = (float*)salloc((size_t)R_*H3_*4);        // 6.3 MB [context | h]
  float* h_steps   = (float*)salloc((size_t)(T_+1)*H_*B_*4);  // 2.2 MB step-indexed [k][b]
  float* dec_steps = (float*)salloc((size_t)T_*B_*A_*4);      // 2.1 MB step-indexed [b][a]
  // total ~116 MB < 204.8 MB -- all consumed before W_v GEMM writes logps

  // d_ws: only buffers live WHILE logps is being written
  char* wp = (char*)d_ws;
  auto walloc = [&](size_t bytes) -> void* {
    void* p = (void*)wp;
    wp += (bytes + 255) & ~(size_t)255;
    return p;
  };
  u16* ah_bf = (u16*)walloc((size_t)R_*H_*2);              // 1.05 MB
  u16* WvT   = (u16*)walloc((size_t)V_*H_*2);              // 51.2 MB
  float2* stats = (float2*)walloc((size_t)R_*NBLKV_*8);    // 3.2 MB
  const size_t ws_fast  = (size_t)R_*H_*2 + (size_t)V_*H_*2 + 512;
  const size_t ws_stats = ws_fast + (size_t)R_*NBLKV_*8 + 256;
  const bool fast_wv   = (ws_size >= ws_fast);
  const bool use_stats = (ws_size >= ws_stats);

  // setup
  k_init0<<<1, 512, 0, stream>>>(bar);
  k_transpose<<<dim3(2,32), 256, 0, stream>>>(W_ih, WihT, H4_, E_);
  k_transpose<<<dim3(8,8), 256, 0, stream>>>(W_dec, W_decT, H_, A_);
  k_gih<<<128, 256, 0, stream>>>(embedded, WihT, b_ih, b_hh, G2);
  k_conv3<<<(B_*S_*H2_/4 + 255)/256, 256, 0, stream>>>(enc, enc3, B_*S_*H2_/4);
  k_convT3<<<dim3(8,16), 256, 0, stream>>>(W_enc, WencT3);
  if (fast_wv)
    k_convT<<<dim3((V_+63)/64, 8), 256, 0, stream>>>(W_v, WvT, H_, V_);

  // enc_proj: single split-bf16 GEMM (K=3072), bf16 output + b_att
  k_gemm_bf16<<<dim3(A_/128, (B_*S_)/128), 256, 0, stream>>>(
      enc3, 3072, WencT3, 3072, b_att, nullptr, ep_bf, A_, B_*S_, A_, 3072, nullptr, 0);

  // fused persistent recurrence: 128 producer + 32 consumer blocks
  k_recur<<<GRB_, 1024, 0, stream>>>(W_hh, G2, W_decT, ep_bf, w_cov, v_att, maskp,
                                     h0, c0, h_steps, dec_steps,
                                     catbuf, attns, covs, bar);

  // deferred contexts + batched tail
  k_ctx<<<dim3(16, 32), 256, 0, stream>>>(attns, enc, catbuf);
  k_ahgemm<<<dim3(8,16), 256, 0, stream>>>(catbuf, W_ah, b_ah, dec_states, fast_wv ? ah_bf : (u16*)nullptr);
  k_pgen<<<128, 512, 0, stream>>>(catbuf, embedded, W_pg, b_pg, pgens);

  // logits
  if (fast_wv)
    k_gemm_bf16<<<dim3(NBLKV_, R_/128), 256, 0, stream>>>(
        ah_bf, H_, WvT, H_, b_v, logps, nullptr, V_, R_, V_, H_,
        use_stats ? stats : nullptr, NBLKV_);
  else
    k_wv_f32<<<dim3((V_+63)/64, R_/64), 256, 0, stream>>>(dec_states, W_v, b_v, logps);

  k_final2<<<R_, 512, 0, stream>>>(logps, pgens, attns, src_tokens,
                                   (fast_wv && use_stats) ? stats : nullptr, NBLKV_);
}

// Round 11
// 1194.889 us; speedup vs baseline: 1.4923x; 1.4923x over previous
//
#include <hip/hip_runtime.h>
#include <hip/hip_bf16.h>
#include <stdint.h>
#include <stddef.h>

#define B_  32
#define S_  400
#define T_  32
#define H_  512
#define E_  128
#define V_  50000
#define A_  512
#define H2_ 1024
#define H3_ 1536
#define H4_ 2048
#define R_  1024     // B*T
#define PGK_ 1664    // 3H+E
#define NBLKV_ 391   // ceil(V/128)
#define GRB_ 128     // persistent-recurrence grid
#define WROW_ 520    // u16 row stride for LDS bf16 tiles (16B-aligned)

typedef unsigned short u16;
typedef short v8s __attribute__((ext_vector_type(8)));
typedef float v4f __attribute__((ext_vector_type(4)));

__device__ __forceinline__ float fsig(float x){ return 1.0f/(1.0f + __expf(-x)); }
__device__ __forceinline__ float ftanh(float x){ float e = __expf(2.0f*x); return 1.0f - 2.0f/(e + 1.0f); }
__device__ __forceinline__ u16 f2bf(float x){ __hip_bfloat16 b = __float2bfloat16(x); return *reinterpret_cast<u16*>(&b); }
__device__ __forceinline__ float bf2f(u16 u){ __hip_bfloat16 b = *reinterpret_cast<__hip_bfloat16*>(&u); return __bfloat162float(b); }

__device__ __forceinline__ float wsum(float v){
  #pragma unroll
  for (int off = 32; off > 0; off >>= 1) v += __shfl_xor(v, off, 64);
  return v;
}
__device__ __forceinline__ float wmax(float v){
  #pragma unroll
  for (int off = 32; off > 0; off >>= 1) v = fmaxf(v, __shfl_xor(v, off, 64));
  return v;
}

#define ALD(p)    __hip_atomic_load((p), __ATOMIC_RELAXED, __HIP_MEMORY_SCOPE_AGENT)
#define AST(p,v)  __hip_atomic_store((p), (v), __ATOMIC_RELAXED, __HIP_MEMORY_SCOPE_AGENT)

// LDS-only barrier: waits lgkmcnt (LDS) but leaves vmem (prefetch) in flight.
__device__ __forceinline__ void ldsbar(){
  asm volatile("s_waitcnt lgkmcnt(0)" ::: "memory");
  __builtin_amdgcn_s_barrier();
  asm volatile("" ::: "memory");
}

// hierarchical fence-free grid barrier: 8 spread counters (16 arrivals each,
// keyed by beta&7) -> 1 global counter (8 arrivals) -> gate. Monotonic counts.
__device__ __forceinline__ void gridbar2(unsigned* bar, unsigned target, int grp){
  __syncthreads();
  if (threadIdx.x == 0){
    unsigned v = __hip_atomic_fetch_add(bar + grp*32, 1u, __ATOMIC_RELAXED, __HIP_MEMORY_SCOPE_AGENT);
    if (v == target*16u - 1u){
      unsigned g2 = __hip_atomic_fetch_add(bar + 256, 1u, __ATOMIC_RELAXED, __HIP_MEMORY_SCOPE_AGENT);
      if (g2 == target*8u - 1u)
        AST(bar + 288, target);
    }
    while (ALD(bar + 288) < target) __builtin_amdgcn_s_sleep(2);
    asm volatile("" ::: "memory");
  }
  __syncthreads();
}

// ---------------- setup kernels ----------------

__global__ void k_init0(unsigned* __restrict__ bar, unsigned long long* __restrict__ mz){
  int t = threadIdx.x;
  if (t < 512) AST(bar + t, 0u);
  if (t < 128) AST(mz + t, 0ull);
}

__global__ __launch_bounds__(256) void k_transpose(const float* __restrict__ in, float* __restrict__ out, int R, int C){
  __shared__ float tile[64][65];
  int c0 = blockIdx.x*64, r0 = blockIdx.y*64;
  int tid = threadIdx.x;
  int cl = tid & 63, q = tid >> 6;
  #pragma unroll
  for (int i=0;i<16;i++){
    int r = q + i*4;
    float v = 0.0f;
    if (r0 + r < R && c0 + cl < C) v = in[(size_t)(r0+r)*C + c0 + cl];
    tile[r][cl] = v;
  }
  __syncthreads();
  #pragma unroll
  for (int i=0;i<16;i++){
    int c = q + i*4;
    if (c0 + c < C && r0 + cl < R)
      out[(size_t)(c0+c)*R + r0 + cl] = tile[cl][c];
  }
}

// f32 [R][C] -> bf16 [C][R] (hi only; used for W_v)
__global__ __launch_bounds__(256) void k_convT(const float* __restrict__ in, u16* __restrict__ hi, int R, int C){
  __shared__ float tile[64][65];
  int c0 = blockIdx.x*64, r0 = blockIdx.y*64;
  int tid = threadIdx.x;
  int cl = tid & 63, q = tid >> 6;
  #pragma unroll
  for (int i=0;i<16;i++){
    int r = q + i*4;
    float v = 0.0f;
    if (r0 + r < R && c0 + cl < C) v = in[(size_t)(r0+r)*C + c0 + cl];
    tile[r][cl] = v;
  }
  __syncthreads();
  #pragma unroll
  for (int i=0;i<16;i++){
    int c = q + i*4;
    if (c0 + c < C && r0 + cl < R)
      hi[(size_t)(c0+c)*R + r0 + cl] = f2bf(tile[cl][c]);
  }
}

// W_enc [1024][512] f32 -> WencT3 [512][3072] bf16 rows = [hi | lo | hi]
__global__ __launch_bounds__(256) void k_convT3(const float* __restrict__ in, u16* __restrict__ out){
  __shared__ float tile[64][65];
  int c0 = blockIdx.x*64, r0 = blockIdx.y*64;   // grid (8,16)
  int tid = threadIdx.x;
  int cl = tid & 63, q = tid >> 6;
  #pragma unroll
  for (int i=0;i<16;i++){
    int r = q + i*4;
    tile[r][cl] = in[(size_t)(r0+r)*A_ + c0 + cl];
  }
  __syncthreads();
  #pragma unroll
  for (int i=0;i<16;i++){
    int c = q + i*4;
    float v = tile[cl][c];
    u16 h = f2bf(v);
    u16 lo = f2bf(v - bf2f(h));
    size_t o = (size_t)(c0+c)*3072 + (r0+cl);
    out[o] = h;
    out[o + 1024] = lo;
    out[o + 2048] = h;
  }
}

// enc [12800][1024] f32 -> enc3 [12800][3072] bf16 rows = [hi | hi | lo]
__global__ void k_conv3(const float* __restrict__ in, u16* __restrict__ out, int n4){
  int i = blockIdx.x*256 + threadIdx.x;
  if (i >= n4) return;
  float4 x = reinterpret_cast<const float4*>(in)[i];
  u16 h0v=f2bf(x.x), h1v=f2bf(x.y), h2v=f2bf(x.z), h3v=f2bf(x.w);
  uint2 hv; hv.x = (unsigned)h0v | ((unsigned)h1v << 16); hv.y = (unsigned)h2v | ((unsigned)h3v << 16);
  uint2 lv;
  lv.x = (unsigned)f2bf(x.x - bf2f(h0v)) | ((unsigned)f2bf(x.y - bf2f(h1v)) << 16);
  lv.y = (unsigned)f2bf(x.z - bf2f(h2v)) | ((unsigned)f2bf(x.w - bf2f(h3v)) << 16);
  int row = i >> 8, c = (i & 255)*4;
  size_t base = (size_t)row*3072 + c;
  *reinterpret_cast<uint2*>(out + base)        = hv;
  *reinterpret_cast<uint2*>(out + base + 1024) = hv;
  *reinterpret_cast<uint2*>(out + base + 2048) = lv;
}

// G2[t][g][hidx][b] = b_ih + b_hh + emb @ W_ih^T   (layout for k_recur coalesced reads)
__global__ __launch_bounds__(256) void k_gih(const float* __restrict__ emb, const float* __restrict__ WihT,
    const float* __restrict__ b_ih, const float* __restrict__ b_hh, float* __restrict__ G){
  __shared__ float em[8][128];
  int r0 = blockIdx.x*8;
  int tid = threadIdx.x;
  #pragma unroll
  for (int i=0;i<4;i++){
    int e = i*256 + tid;
    em[e>>7][e&127] = emb[(size_t)(r0 + (e>>7))*E_ + (e&127)];
  }
  __syncthreads();
  for (int jj=0;jj<8;jj++){
    int j = jj*256 + tid;
    float bias = b_ih[j] + b_hh[j];
    float acc[8];
    #pragma unroll
    for (int r=0;r<8;r++) acc[r] = bias;
    for (int e=0;e<128;e++){
      float wv = WihT[(size_t)e*H4_ + j];
      #pragma unroll
      for (int r=0;r<8;r++) acc[r] += em[r][e]*wv;
    }
    #pragma unroll
    for (int rr=0;rr<8;rr++){
      int r = r0 + rr;
      G[(size_t)(r & 31)*65536 + (size_t)(j >> 9)*16384 + (size_t)(j & 511)*32 + (r >> 5)] = acc[rr];
    }
  }
}

// ---------------- MFMA bf16 GEMM (coalesced LDS epilogue, optional stats) ----------------
__global__ __launch_bounds__(256, 2) void k_gemm_bf16(
    const u16* __restrict__ A, int lda, const u16* __restrict__ Bt, int ldb,
    const float* __restrict__ bias, float* __restrict__ Cf, u16* __restrict__ Cbf, int ldc,
    int M, int N, int K, float2* __restrict__ stats, int nblk)
{
  __shared__ __align__(16) float CsF[128*132];
  __shared__ float rs[128], rs2[128];
  u16* As = reinterpret_cast<u16*>(CsF);
  u16* Bs = As + 128*64;
  const int tid = threadIdx.x;
  const int m0 = blockIdx.y * 128;
  const int n0 = blockIdx.x * 128;
  const int l  = tid & 63;
  const int wavebase = tid & ~63;
  const int wid = tid >> 6;
  const int wm = (wid >> 1) * 64;
  const int wn = (wid & 1) * 64;

  v4f acc[4][4];
  v4f vzero = {0.0f, 0.0f, 0.0f, 0.0f};
  #pragma unroll
  for (int i=0;i<4;i++)
    #pragma unroll
    for (int j=0;j<4;j++) acc[i][j] = vzero;

  for (int k0 = 0; k0 < K; k0 += 64){
    __syncthreads();
    #pragma unroll
    for (int jj=0;jj<4;jj++){
      int fc = jj*256 + tid;
      int row = fc >> 3;
      int cc = (fc & 7) ^ (row & 7);
      const u16* g = A + (size_t)(m0 + row)*lda + k0 + cc*8;
      __builtin_amdgcn_global_load_lds(
        (__attribute__((address_space(1))) void*)g,
        (__attribute__((address_space(3))) void*)(As + (size_t)(jj*256 + wavebase)*8),
        16, 0, 0);
    }
    #pragma unroll
    for (int jj=0;jj<4;jj++){
      int fc = jj*256 + tid;
      int row = fc >> 3;
      int cc = (fc & 7) ^ (row & 7);
      int rn = n0 + row; if (rn > N-1) rn = N-1;
      const u16* g = Bt + (size_t)rn*ldb + k0 + cc*8;
      __builtin_amdgcn_global_load_lds(
        (__attribute__((address_space(1))) void*)g,
        (__attribute__((address_space(3))) void*)(Bs + (size_t)(jj*256 + wavebase)*8),
        16, 0, 0);
    }
    __syncthreads();
    #pragma unroll
    for (int ks=0;ks<2;ks++){
      v8s af[4], bfr[4];
      #pragma unroll
      for (int rt=0;rt<4;rt++){
        int r = wm + rt*16 + (l & 15);
        int cs = (ks*4 + (l >> 4)) ^ (r & 7);
        af[rt] = *reinterpret_cast<const v8s*>(As + r*64 + cs*8);
      }
      #pragma unroll
      for (int nt=0;nt<4;nt++){
        int r = wn + nt*16 + (l & 15);
        int cs = (ks*4 + (l >> 4)) ^ (r & 7);
        bfr[nt] = *reinterpret_cast<const v8s*>(Bs + r*64 + cs*8);
      }
      #pragma unroll
      for (int rt=0;rt<4;rt++)
        #pragma unroll
        for (int nt=0;nt<4;nt++)
          acc[rt][nt] = __builtin_amdgcn_mfma_f32_16x16x32_bf16(af[rt], bfr[nt], acc[rt][nt], 0, 0, 0);
    }
  }

  const int cl = l & 15;
  const int rg = (l >> 4) * 4;
  float cvv[4][4][4];
  #pragma unroll
  for (int rt=0;rt<4;rt++)
    #pragma unroll
    for (int nt=0;nt<4;nt++){
      int gc = n0 + wn + nt*16 + cl;
      float bv = (bias && gc < N) ? bias[gc] : 0.0f;
      #pragma unroll
      for (int i=0;i<4;i++) cvv[rt][nt][i] = acc[rt][nt][i] + bv;
    }

  if (stats){
    float tsm[4][4];
    #pragma unroll
    for (int rt=0;rt<4;rt++)
      #pragma unroll
      for (int i=0;i<4;i++){
        float mx = -1e30f;
        #pragma unroll
        for (int nt=0;nt<4;nt++){
          int gc = n0 + wn + nt*16 + cl;
          if (gc < N) mx = fmaxf(mx, cvv[rt][nt][i]);
        }
        #pragma unroll
        for (int off=1; off<16; off<<=1) mx = fmaxf(mx, __shfl_xor(mx, off, 64));
        if (wn == 0 && cl == 0) rs[wm + rt*16 + rg + i] = mx;
        tsm[rt][i] = mx;
      }
    __syncthreads();
    if (wn != 0){
      #pragma unroll
      for (int rt=0;rt<4;rt++)
        #pragma unroll
        for (int i=0;i<4;i++){
          float c = fmaxf(tsm[rt][i], rs[wm + rt*16 + rg + i]);
          if (cl == 0) rs[wm + rt*16 + rg + i] = c;
        }
    }
    __syncthreads();
    #pragma unroll
    for (int rt=0;rt<4;rt++)
      #pragma unroll
      for (int i=0;i<4;i++){
        float rm = rs[wm + rt*16 + rg + i];
        float sm = 0.0f;
        #pragma unroll
        for (int nt=0;nt<4;nt++){
          int gc = n0 + wn + nt*16 + cl;
          if (gc < N) sm += __expf(cvv[rt][nt][i] - rm);
        }
        #pragma unroll
        for (int off=1; off<16; off<<=1) sm += __shfl_xor(sm, off, 64);
        tsm[rt][i] = sm;
        if (wn == 0 && cl == 0) rs2[wm + rt*16 + rg + i] = sm;
      }
    __syncthreads();
    if (wn != 0 && cl == 0){
      #pragma unroll
      for (int rt=0;rt<4;rt++)
        #pragma unroll
        for (int i=0;i<4;i++){
          int row = wm + rt*16 + rg + i;
          stats[(size_t)(m0 + row)*nblk + blockIdx.x] =
            make_float2(rs[row], tsm[rt][i] + rs2[row]);
        }
    }
  }

  __syncthreads();
  #pragma unroll
  for (int rt=0;rt<4;rt++)
    #pragma unroll
    for (int nt=0;nt<4;nt++)
      #pragma unroll
      for (int i=0;i<4;i++)
        CsF[(wm + rt*16 + rg + i)*132 + wn + nt*16 + cl] = cvv[rt][nt][i];
  __syncthreads();
  #pragma unroll
  for (int it=0; it<16; ++it){
    int row = (tid >> 5) + it*8;
    int c4 = tid & 31;
    int gc = n0 + c4*4;
    int gr = m0 + row;
    if (gc < N){
      float4 v = *reinterpret_cast<const float4*>(&CsF[row*132 + c4*4]);
      if (Cf) *reinterpret_cast<float4*>(Cf + (size_t)gr*ldc + gc) = v;
      if (Cbf){
        uint2 o;
        o.x = (unsigned)f2bf(v.x) | ((unsigned)f2bf(v.y) << 16);
        o.y = (unsigned)f2bf(v.z) | ((unsigned)f2bf(v.w) << 16);
        *reinterpret_cast<uint2*>(Cbf + (size_t)gr*ldc + gc) = o;
      }
    }
  }
}

// fallback f32 GEMM for W_v when ws too small
__global__ __launch_bounds__(256) void k_wv_f32(
  const float* __restrict__ Aah, const float* __restrict__ Wv, const float* __restrict__ bv,
  float* __restrict__ Cl)
{
  __shared__ float Asf[32][68];
  __shared__ float Bsf[32][64];
  int n0 = blockIdx.x*64, m0 = blockIdx.y*64;
  int tid = threadIdx.x;
  int tx = tid & 15, ty = tid >> 4;
  float acc[4][4] = {};
  for (int kc = 0; kc < H_; kc += 32){
    __syncthreads();
    #pragma unroll
    for (int i=0;i<8;i++){
      int e = i*256 + tid;
      Asf[e & 31][e >> 5] = Aah[(size_t)(m0 + (e >> 5))*H_ + kc + (e & 31)];
    }
    #pragma unroll
    for (int i=0;i<8;i++){
      int e = i*256 + tid;
      int nc = n0 + (e & 63); if (nc >= V_) nc = V_-1;
      Bsf[e >> 6][e & 63] = Wv[(size_t)(kc + (e >> 6))*V_ + nc];
    }
    __syncthreads();
    #pragma unroll
    for (int k=0;k<32;k++){
      float4 a4 = *reinterpret_cast<const float4*>(&Asf[k][ty*4]);
      float4 b4 = *reinterpret_cast<const float4*>(&Bsf[k][tx*4]);
      float av[4] = {a4.x, a4.y, a4.z, a4.w};
      float bv4[4] = {b4.x, b4.y, b4.z, b4.w};
      #pragma unroll
      for (int i=0;i<4;i++)
        #pragma unroll
        for (int j=0;j<4;j++)
          acc[i][j] = __builtin_fmaf(av[i], bv4[j], acc[i][j]);
    }
  }
  #pragma unroll
  for (int i=0;i<4;i++){
    int rr = m0 + ty*4 + i;
    #pragma unroll
    for (int j=0;j<4;j++){
      int cc = n0 + tx*4 + j;
      if (cc < V_) Cl[(size_t)rr*V_ + cc] = acc[i][j] + bv[cc];
    }
  }
}

// ---------------- persistent fused recurrence (MFMA X-phase; r9 proven) ----------------
// iter i: [cvt h->bf16 hi/lo LDS] ldsbar [4 waves: 3-pass split-bf16 MFMA
// (20x32x512) -> gv2 + dec publish] ldsbar [LSTM -> publish h] gridbar
// [prefetch h_{i+1} regs] [Y: scores_{i-1}, tag-spin stats, softmax, attn/cov]
__global__ __launch_bounds__(1024) void k_recur(
  const float* __restrict__ W_hh, const float* __restrict__ G2,
  const float* __restrict__ W_decT, const u16* __restrict__ ep_bf,
  const float* __restrict__ w_cov, const float* __restrict__ v_att,
  const void* __restrict__ maskp, const float* __restrict__ h0,
  const float* __restrict__ c0, float* __restrict__ h_gT,
  float* __restrict__ dec_g, unsigned long long* __restrict__ mz,
  float* __restrict__ catbuf, float* __restrict__ attns, float* __restrict__ covs,
  unsigned* __restrict__ bar)
{
  const int beta = blockIdx.x;
  const int tid = threadIdx.x;
  __shared__ __align__(16) u16 Whi[32*WROW_];   // rows: 16 gate, 4 dec, 12 zero
  __shared__ __align__(16) u16 Wlo[32*WROW_];
  __shared__ __align__(16) u16 Hhi[32*WROW_];   // [b][k] bf16
  __shared__ __align__(16) u16 Hlo[32*WROW_];
  __shared__ float gv2[16][32];
  __shared__ float c_l[128];
  __shared__ float dec_l[512];
  __shared__ float sc_l[100];
  __shared__ float cov_l[100];
  __shared__ float smz[4][2];

  const int b32 = tid & 31;
  const int w = tid >> 6, l = tid & 63;
  const int grp = beta & 7;            // barrier arrival group
  const int bb = (beta & 7)*4 + (beta >> 5);
  const int sq = (beta >> 3) & 3;
  const int b2 = (tid & 15)*2;         // cvt/prefetch: batch pair
  const int kg = tid >> 4;             // cvt/prefetch: k-octet 0..63

  // one-time staging: W rows (16 gates + 4 dec + 12 zero) as bf16 hi/lo
  for (int idx = tid; idx < 32*512; idx += 1024){
    int row = idx >> 9;
    int k = idx & 511;
    float v = 0.0f;
    if (row < 16)      v = W_hh[((size_t)(row >> 2)*H_ + beta*4 + (row & 3))*H_ + k];
    else if (row < 20) v = W_decT[(size_t)(beta*4 + (row - 16))*H_ + k];
    u16 h = f2bf(v);
    Whi[row*WROW_ + k] = h;
    Wlo[row*WROW_ + k] = f2bf(v - bf2f(h));
  }
  if (tid < 128) c_l[tid] = c0[(size_t)(tid & 31)*H_ + beta*4 + (tid >> 5)];
  if (tid < 100) cov_l[tid] = 0.f;

  const unsigned* m32p = (const unsigned*)maskp;
  const unsigned char* m8p = (const unsigned char*)maskp;
  const bool bytemode = (m32p[0] == 0x01010101u);

  float wc8[8], va8[8];
  {
    int a0 = l*8;
    #pragma unroll
    for (int j=0;j<8;j++){ wc8[j] = w_cov[a0+j]; va8[j] = v_att[a0+j]; }
  }

  // prologue: h_state[0] from h0 ([b][k] layout)
  float hA[8], hB[8];
  unsigned long long hld[8];
  #pragma unroll
  for (int kk=0;kk<8;kk++){
    int k = kg*8 + kk;
    hA[kk] = h0[(size_t)b2*H_ + k];
    hB[kk] = h0[(size_t)(b2+1)*H_ + k];
  }

  unsigned gen = 0;
  for (int i = 0; i <= T_; ++i){
    const int par = i & 1;
    // ---- cvt h -> bf16 hi/lo, write [b][k] rows ----
    {
      v8s phA, plA, phB, plB;
      #pragma unroll
      for (int kk=0;kk<8;kk++){
        float va = hA[kk], vb = hB[kk];
        u16 ha = f2bf(va), hb = f2bf(vb);
        phA[kk] = (short)ha; plA[kk] = (short)f2bf(va - bf2f(ha));
        phB[kk] = (short)hb; plB[kk] = (short)f2bf(vb - bf2f(hb));
      }
      *reinterpret_cast<v8s*>(Hhi + (size_t)b2*WROW_ + kg*8) = phA;
      *reinterpret_cast<v8s*>(Hlo + (size_t)b2*WROW_ + kg*8) = plA;
      *reinterpret_cast<v8s*>(Hhi + (size_t)(b2+1)*WROW_ + kg*8) = phB;
      *reinterpret_cast<v8s*>(Hlo + (size_t)(b2+1)*WROW_ + kg*8) = plB;
    }
    ldsbar();

    // ---- MFMA gates+dec: D[20x32] = W · h^T, split-bf16 3 passes ----
    if (w < 4){
      const int mt = w >> 1, nt = w & 1;
      const int fr = (l & 15);
      const int fo = (l >> 4)*8;
      const u16* Ahi = Whi + (size_t)(mt*16 + fr)*WROW_ + fo;
      const u16* Alo = Wlo + (size_t)(mt*16 + fr)*WROW_ + fo;
      const u16* Bhi = Hhi + (size_t)(nt*16 + fr)*WROW_ + fo;
      const u16* Blo = Hlo + (size_t)(nt*16 + fr)*WROW_ + fo;
      v4f a0 = {0.f,0.f,0.f,0.f}, a1 = a0, a2 = a0;
      #pragma unroll
      for (int ks=0; ks<16; ks++){
        v8s wh = *reinterpret_cast<const v8s*>(Ahi + ks*32);
        v8s wl = *reinterpret_cast<const v8s*>(Alo + ks*32);
        v8s hh = *reinterpret_cast<const v8s*>(Bhi + ks*32);
        v8s hl = *reinterpret_cast<const v8s*>(Blo + ks*32);
        a0 = __builtin_amdgcn_mfma_f32_16x16x32_bf16(wh, hh, a0, 0, 0, 0);
        a1 = __builtin_amdgcn_mfma_f32_16x16x32_bf16(wh, hl, a1, 0, 0, 0);
        a2 = __builtin_amdgcn_mfma_f32_16x16x32_bf16(wl, hh, a2, 0, 0, 0);
      }
      v4f acc = a0 + a1 + a2;
      if (mt == 0){
        int col = nt*16 + fr;
        int r0w = (l >> 4)*4;
        #pragma unroll
        for (int q=0;q<4;q++) gv2[r0w + q][col] = acc[q];
      } else if ((l >> 4) == 0){
        int b = nt*16 + fr;
        float* dg = dec_g + (size_t)par*B_*A_ + (size_t)b*A_ + beta*4;
        unsigned long long p0 = ((unsigned long long)__float_as_uint(acc[1]) << 32) | __float_as_uint(acc[0]);
        unsigned long long p1 = ((unsigned long long)__float_as_uint(acc[3]) << 32) | __float_as_uint(acc[2]);
        AST(reinterpret_cast<unsigned long long*>(dg), p0);
        AST(reinterpret_cast<unsigned long long*>(dg + 2), p1);
      }
    }
    ldsbar();

    // ---- LSTM pointwise + publish h ----
    if (i < T_ && tid < 128){
      int hh = tid >> 5;
      int hidx = beta*4 + hh;
      const float* Gr = G2 + (size_t)i*65536 + (size_t)hidx*32 + b32;
      float gi = gv2[0*4+hh][b32] + Gr[0];
      float gf = gv2[1*4+hh][b32] + Gr[16384];
      float gz = gv2[2*4+hh][b32] + Gr[32768];
      float go = gv2[3*4+hh][b32] + Gr[49152];
      float co = c_l[tid];
      float cn = fsig(gf)*co + fsig(gi)*ftanh(gz);
      float hn = fsig(go)*ftanh(cn);
      c_l[tid] = cn;
      AST(h_gT + (size_t)(par^1)*16384 + (size_t)hidx*32 + b32, hn);
      catbuf[(size_t)(b32*T_ + i)*H3_ + H2_ + hidx] = hn;
    }
    gridbar2(bar, ++gen, grp);

    // ---- prefetch h_{i+1} (overlaps Y) ----
    if (i < T_){
      const unsigned long long* hp =
        reinterpret_cast<const unsigned long long*>(h_gT + (size_t)(par^1)*16384);
      #pragma unroll
      for (int kk=0;kk<8;kk++)
        hld[kk] = ALD(hp + (size_t)(kg*8 + kk)*16 + (b2 >> 1));
    }

    // ---- Y: scores_{i-1} for s-quarter sq of batch bb ----
    if (i > 0){
      const int r = bb*T_ + (i-1);
      if (tid < 512) dec_l[tid] = ALD(dec_g + (size_t)par*B_*A_ + (size_t)bb*A_ + tid);
      ldsbar();
      int a0i = l*8;
      float dec8[8];
      #pragma unroll
      for (int j=0;j<8;j++) dec8[j] = dec_l[a0i+j];
      #pragma unroll
      for (int it=0; it<7; ++it){
        int sl = w + it*16;
        if (sl < 100){
          int s = sq*100 + sl;
          float cv = cov_l[sl];
          uint4 e8 = *reinterpret_cast<const uint4*>(ep_bf + (size_t)(bb*S_ + s)*A_ + a0i);
          unsigned uu[4] = {e8.x, e8.y, e8.z, e8.w};
          float part = 0.f;
          #pragma unroll
          for (int j=0;j<4;j++){
            float xa = bf2f((u16)(uu[j] & 0xFFFFu)) + dec8[2*j]   + cv*wc8[2*j];
            part += va8[2*j]*ftanh(xa);
            float xb = bf2f((u16)(uu[j] >> 16))     + dec8[2*j+1] + cv*wc8[2*j+1];
            part += va8[2*j+1]*ftanh(xb);
          }
          part = wsum(part);
          if (l == 0){
            bool on = bytemode ? (m8p[bb*S_+s] != 0) : (m32p[bb*S_+s] != 0u);
            sc_l[sl] = on ? part : -1e9f;
          }
        }
      }
      __syncthreads();
      // local (m,Z); publish with gen tag in Z low mantissa bits
      if (tid < 64){
        float x1v = sc_l[l];
        float x2v = (l + 64 < 100) ? sc_l[l + 64] : -1e30f;
        float m = wmax(fmaxf(x1v, x2v));
        float z = __expf(x1v - m) + ((l + 64 < 100) ? __expf(x2v - m) : 0.f);
        z = wsum(z);
        if (l == 0){
          unsigned zt = (__float_as_uint(z) & ~255u) | (gen & 255u);
          unsigned long long pk = ((unsigned long long)zt << 32) | (unsigned long long)__float_as_uint(m);
          AST(mz + bb*4 + sq, pk);
        }
      }
      if (tid < 4){
        unsigned long long v;
        do {
          v = ALD(mz + bb*4 + tid);
          if (((unsigned)(v >> 32) & 255u) == (gen & 255u)) break;
          __builtin_amdgcn_s_sleep(1);
        } while (true);
        smz[tid][0] = __uint_as_float((unsigned)v);
        smz[tid][1] = __uint_as_float((unsigned)(v >> 32));
      }
      __syncthreads();
      float gm = fmaxf(fmaxf(smz[0][0], smz[1][0]), fmaxf(smz[2][0], smz[3][0]));
      float gZ = smz[0][1]*__expf(smz[0][0]-gm) + smz[1][1]*__expf(smz[1][0]-gm)
               + smz[2][1]*__expf(smz[2][0]-gm) + smz[3][1]*__expf(smz[3][0]-gm);
      float invZ = 1.f/gZ;
      if (tid < 100){
        float av = __expf(sc_l[tid] - gm)*invZ;
        int s = sq*100 + tid;
        float cn = cov_l[tid] + av;
        cov_l[tid] = cn;
        attns[(size_t)r*S_ + s] = av;
        covs[(size_t)r*S_ + s]  = cn;
      }
      __syncthreads();
    }

    // ---- unpack prefetched h for next iteration ----
    if (i < T_){
      #pragma unroll
      for (int kk=0;kk<8;kk++){
        hA[kk] = __uint_as_float((unsigned)hld[kk]);
        hB[kk] = __uint_as_float((unsigned)(hld[kk] >> 32));
      }
    }
  }
}

// ---------------- post-loop kernels ----------------

// context (deferred): catbuf[:, :1024] = attns @ enc   (fp32, single enc pass)
__global__ __launch_bounds__(256, 2) void k_ctx(
  const float* __restrict__ attns, const float* __restrict__ enc, float* __restrict__ catbuf)
{
  __shared__ float att_s[32][400];
  int d0 = blockIdx.x*64, b = blockIdx.y;
  int tid = threadIdx.x;
  for (int tt=0; tt<32; ++tt)
    for (int s = tid; s < S_; s += 256)
      att_s[tt][s] = attns[(size_t)(b*T_ + tt)*S_ + s];
  __syncthreads();
  int d = d0 + (tid & 63);
  int t0 = (tid >> 6)*8;
  float acc[8] = {0,0,0,0,0,0,0,0};
  const float* encb = enc + (size_t)b*S_*H2_ + d;
  #pragma unroll 4
  for (int s=0; s<S_; ++s){
    float ev = encb[(size_t)s*H2_];
    #pragma unroll
    for (int i=0;i<8;i++) acc[i] = __builtin_fmaf(att_s[t0+i][s], ev, acc[i]);
  }
  #pragma unroll
  for (int i=0;i<8;i++)
    catbuf[(size_t)(b*T_ + t0 + i)*H3_ + d] = acc[i];
}

// fp32 tiled GEMM: dec_states = tanh(catbuf @ W_ah + b_ah); optional bf16 copy
__global__ __launch_bounds__(256) void k_ahgemm(
  const float* __restrict__ Acat, const float* __restrict__ W_ah, const float* __restrict__ b_ah,
  float* __restrict__ dec_states, u16* __restrict__ ah_bf)
{
  __shared__ float Asf[32][68];
  __shared__ float Bsf[32][64];
  int n0 = blockIdx.x*64, m0 = blockIdx.y*64;
  int tid = threadIdx.x;
  int tx = tid & 15, ty = tid >> 4;
  float acc[4][4] = {};
  for (int kc = 0; kc < H3_; kc += 32){
    __syncthreads();
    #pragma unroll
    for (int i=0;i<8;i++){
      int e = i*256 + tid;
      Asf[e & 31][e >> 5] = Acat[(size_t)(m0 + (e >> 5))*H3_ + kc + (e & 31)];
    }
    #pragma unroll
    for (int i=0;i<8;i++){
      int e = i*256 + tid;
      Bsf[e >> 6][e & 63] = W_ah[(size_t)(kc + (e >> 6))*H_ + n0 + (e & 63)];
    }
    __syncthreads();
    #pragma unroll
    for (int k=0;k<32;k++){
      float4 a4 = *reinterpret_cast<const float4*>(&Asf[k][ty*4]);
      float4 b4 = *reinterpret_cast<const float4*>(&Bsf[k][tx*4]);
      float av[4] = {a4.x, a4.y, a4.z, a4.w};
      float bv[4] = {b4.x, b4.y, b4.z, b4.w};
      #pragma unroll
      for (int i=0;i<4;i++)
        #pragma unroll
        for (int j=0;j<4;j++)
          acc[i][j] = __builtin_fmaf(av[i], bv[j], acc[i][j]);
    }
  }
  #pragma unroll
  for (int i=0;i<4;i++){
    int rr = m0 + ty*4 + i;
    #pragma unroll
    for (int j=0;j<4;j++){
      int cc = n0 + tx*4 + j;
      float v = ftanh(acc[i][j] + b_ah[cc]);
      dec_states[(size_t)rr*H_ + cc] = v;
      if (ah_bf) ah_bf[(size_t)rr*H_ + cc] = f2bf(v);
    }
  }
}

__global__ __launch_bounds__(512) void k_pgen(const float* __restrict__ catbuf, const float* __restrict__ emb,
  const float* __restrict__ W_pg, const float* __restrict__ b_pg, float* __restrict__ pgens)
{
  int w = threadIdx.x >> 6, l = threadIdx.x & 63;
  int r = blockIdx.x*8 + w;
  float part = 0.0f;
  for (int d = l; d < PGK_; d += 64){
    float x = (d < H3_) ? catbuf[(size_t)r*H3_ + d] : emb[(size_t)r*E_ + (d - H3_)];
    part += x*W_pg[d];
  }
  part = wsum(part);
  if (l == 0) pgens[r] = fsig(part + b_pg[0]);
}

// per-row final: stats merge -> bitmask+hash scatter -> fast log transform
__global__ __launch_bounds__(512) void k_final2(
  float* __restrict__ logits, const float* __restrict__ pgens,
  const float* __restrict__ attns, const int* __restrict__ src,
  const float2* __restrict__ stats, int nblk)
{
  __shared__ unsigned bits[1568];
  __shared__ unsigned keys[1024];
  __shared__ float vals[1024];
  __shared__ float sred[18];
  int r = blockIdx.x;
  int b = r >> 5;
  int tid = threadIdx.x;
  int w = tid >> 6, l = tid & 63;
  float* row = logits + (size_t)r*V_;

  for (int i = tid; i < 1568; i += 512) bits[i] = 0u;
  for (int i = tid; i < 1024; i += 512){ keys[i] = 0xFFFFFFFFu; vals[i] = 0.0f; }

  if (stats){
    float m = -1e30f, Z = 0.0f;
    if (tid < nblk){ float2 st = stats[(size_t)r*nblk + tid]; m = st.x; Z = st.y; }
    #pragma unroll
    for (int off=32; off>0; off>>=1){
      float mo = __shfl_xor(m, off, 64);
      float Zo = __shfl_xor(Z, off, 64);
      float nm = fmaxf(m, mo);
      Z = Z*__expf(m - nm) + Zo*__expf(mo - nm);
      m = nm;
    }
    if (l == 0){ sred[w*2] = m; sred[w*2+1] = Z; }
    __syncthreads();
    if (tid == 0){
      float gm = -1e30f, gz = 0.0f;
      #pragma unroll
      for (int i=0;i<8;i++){
        float mi = sred[i*2], zi = sred[i*2+1];
        float nm = fmaxf(gm, mi);
        gz = gz*__expf(gm - nm) + zi*__expf(mi - nm);
        gm = nm;
      }
      sred[16] = gm; sred[17] = gz;
    }
    __syncthreads();
  } else {
    float m = -1e30f;
    for (int j = tid; j < V_/4; j += 512){
      float4 x = reinterpret_cast<const float4*>(row)[j];
      m = fmaxf(fmaxf(m, x.x), fmaxf(fmaxf(x.y, x.z), x.w));
    }
    m = wmax(m);
    if (l == 0) sred[w] = m;
    __syncthreads();
    if (tid == 0){
      float gm = -1e30f;
      #pragma unroll
      for (int i=0;i<8;i++) gm = fmaxf(gm, sred[i]);
      sred[16] = gm;
    }
    __syncthreads();
    float gm = sred[16];
    float z = 0.0f;
    for (int j = tid; j < V_/4; j += 512){
      float4 x = reinterpret_cast<const float4*>(row)[j];
      z += __expf(x.x-gm) + __expf(x.y-gm) + __expf(x.z-gm) + __expf(x.w-gm);
    }
    z = wsum(z);
    if (l == 0) sred[8 + w] = z;
    __syncthreads();
    if (tid == 0){
      float gz = 0.0f;
      #pragma unroll
      for (int i=0;i<8;i++) gz += sred[8 + i];
      sred[17] = gz;
    }
    __syncthreads();
  }

  float gm = sred[16];
  float gZ = sred[17];
  float pg = pgens[r];
  float scale = pg / gZ;
  float lscale = __logf(scale);

  if (tid < S_){
    int tok = src[b*S_ + tid];
    float add = (1.0f - pg)*attns[(size_t)r*S_ + tid];
    atomicOr(&bits[tok >> 5], 1u << (tok & 31));
    unsigned h = ((unsigned)tok * 2654435761u) >> 22;
    while (true){
      unsigned prev = atomicCAS(&keys[h], 0xFFFFFFFFu, (unsigned)tok);
      if (prev == 0xFFFFFFFFu || prev == (unsigned)tok){
        atomicAdd(&vals[h], add);
        break;
      }
      h = (h + 1) & 1023;
    }
  }
  __syncthreads();

  for (int j = tid; j < V_/4; j += 512){
    float4 x = reinterpret_cast<const float4*>(row)[j];
    int v = 4*j;
    float o[4];
    float xv[4] = {x.x, x.y, x.z, x.w};
    #pragma unroll
    for (int k=0;k<4;k++){
      int vv = v + k;
      bool hit = (bits[vv >> 5] >> (vv & 31)) & 1u;
      float tt = xv[k] - gm + lscale;
      if (!hit && tt > -25.0f){
        o[k] = tt;
      } else {
        float pval = __expf(xv[k] - gm)*scale;
        if (hit){
          unsigned h = ((unsigned)vv * 2654435761u) >> 22;
          while (keys[h] != 0xFFFFFFFFu){
            if (keys[h] == (unsigned)vv){ pval += vals[h]; break; }
            h = (h + 1) & 1023;
          }
        }
        o[k] = __logf(pval + 1e-20f);
      }
    }
    reinterpret_cast<float4*>(row)[j] = make_float4(o[0], o[1], o[2], o[3]);
  }
}

// ---------------- host ----------------

extern "C" void kernel_launch(void* const* d_in, const int* in_sizes, int n_in,
                              void* d_out, int out_size, void* d_ws, size_t ws_size,
                              hipStream_t stream)
{
  const int* src_tokens = (const int*)d_in[0];
  const float* embedded = (const float*)d_in[1];
  const float* enc      = (const float*)d_in[2];
  const void*  maskp    = (const void*)d_in[3];
  const float* h0  = (const float*)d_in[4];
  const float* c0  = (const float*)d_in[5];
  const float* W_ih = (const float*)d_in[6];
  const float* W_hh = (const float*)d_in[7];
  const float* b_ih = (const float*)d_in[8];
  const float* b_hh = (const float*)d_in[9];
  const float* W_enc = (const float*)d_in[10];
  const float* W_dec = (const float*)d_in[11];
  const float* w_cov = (const float*)d_in[12];
  const float* b_att = (const float*)d_in[13];
  const float* v_att = (const float*)d_in[14];
  const float* W_ah  = (const float*)d_in[15];
  const float* b_ah  = (const float*)d_in[16];
  const float* W_pg  = (const float*)d_in[17];
  const float* b_pg  = (const float*)d_in[18];
  const float* W_v   = (const float*)d_in[19];
  const float* b_v   = (const float*)d_in[20];
  (void)in_sizes; (void)n_in; (void)out_size;

  float* outp = (float*)d_out;
  float* logps = outp;                                  // (B,T,V)   204.8 MB
  float* dec_states = logps + (size_t)R_*V_;            // (B,T,H)
  float* attns = dec_states + (size_t)R_*H_;            // (B,T,S)
  float* covs  = attns + (size_t)R_*S_;                 // (B,T,S)
  float* pgens = covs + (size_t)R_*S_;                  // (B,T)

  // big transients live INSIDE the logps output region (dead until W_v GEMM)
  char* sp = (char*)logps;
  auto salloc = [&](size_t bytes) -> void* {
    void* p = (void*)sp;
    sp += (bytes + 255) & ~(size_t)255;
    return p;
  };
  unsigned* bar = (unsigned*)salloc(2048);
  unsigned long long* mz = (unsigned long long*)salloc((size_t)B_*4*8);
  u16* ep_bf    = (u16*)salloc((size_t)B_*S_*A_*2);        // 13.1 MB
  u16* enc3     = (u16*)salloc((size_t)B_*S_*3072*2);      // 78.6 MB
  u16* WencT3   = (u16*)salloc((size_t)A_*3072*2);         // 3.1 MB
  float* WihT   = (float*)salloc((size_t)E_*H4_*4);        // 1 MB
  float* W_decT = (float*)salloc((size_t)H_*A_*4);         // 1 MB
  float* G2     = (float*)salloc((size_t)R_*H4_*4);        // 8.4 MB [t][g][hidx][b]
  float* catbuf = (float*)salloc((size_t)R_*H3_*4);        // 6.3 MB [context | h]
  float* dec_g  = (float*)salloc((size_t)2*B_*A_*4);       // 128 KB double-buffered
  float* h_gT   = (float*)salloc((size_t)2*H_*B_*4);       // 128 KB double-buffered [k][b]
  // total ~112 MB < 204.8 MB -- all consumed before W_v GEMM writes logps

  // d_ws: only buffers live WHILE logps is being written
  char* wp = (char*)d_ws;
  auto walloc = [&](size_t bytes) -> void* {
    void* p = (void*)wp;
    wp += (bytes + 255) & ~(size_t)255;
    return p;
  };
  u16* ah_bf = (u16*)walloc((size_t)R_*H_*2);              // 1.05 MB
  u16* WvT   = (u16*)walloc((size_t)V_*H_*2);              // 51.2 MB
  float2* stats = (float2*)walloc((size_t)R_*NBLKV_*8);    // 3.2 MB
  const size_t ws_fast  = (size_t)R_*H_*2 + (size_t)V_*H_*2 + 512;
  const size_t ws_stats = ws_fast + (size_t)R_*NBLKV_*8 + 256;
  const bool fast_wv   = (ws_size >= ws_fast);
  const bool use_stats = (ws_size >= ws_stats);

  // setup
  k_init0<<<1, 512, 0, stream>>>(bar, mz);
  k_transpose<<<dim3(2,32), 256, 0, stream>>>(W_ih, WihT, H4_, E_);
  k_transpose<<<dim3(8,8), 256, 0, stream>>>(W_dec, W_decT, H_, A_);
  k_gih<<<128, 256, 0, stream>>>(embedded, WihT, b_ih, b_hh, G2);
  k_conv3<<<(B_*S_*H2_/4 + 255)/256, 256, 0, stream>>>(enc, enc3, B_*S_*H2_/4);
  k_convT3<<<dim3(8,16), 256, 0, stream>>>(W_enc, WencT3);
  if (fast_wv)
    k_convT<<<dim3((V_+63)/64, 8), 256, 0, stream>>>(W_v, WvT, H_, V_);

  // enc_proj: single split-bf16 GEMM (K=3072), bf16 output + b_att
  k_gemm_bf16<<<dim3(A_/128, (B_*S_)/128), 256, 0, stream>>>(
      enc3, 3072, WencT3, 3072, b_att, nullptr, ep_bf, A_, B_*S_, A_, 3072, nullptr, 0);

  // fused persistent recurrence (MFMA X-phase, 1024 threads) — r9 proven version
  k_recur<<<GRB_, 1024, 0, stream>>>(W_hh, G2, W_decT, ep_bf, w_cov, v_att, maskp,
                                     h0, c0, h_gT, dec_g, mz,
                                     catbuf, attns, covs, bar);

  // deferred contexts + batched tail
  k_ctx<<<dim3(16, 32), 256, 0, stream>>>(attns, enc, catbuf);
  k_ahgemm<<<dim3(8,16), 256, 0, stream>>>(catbuf, W_ah, b_ah, dec_states, fast_wv ? ah_bf : (u16*)nullptr);
  k_pgen<<<128, 512, 0, stream>>>(catbuf, embedded, W_pg, b_pg, pgens);

  // logits
  if (fast_wv)
    k_gemm_bf16<<<dim3(NBLKV_, R_/128), 256, 0, stream>>>(
        ah_bf, H_, WvT, H_, b_v, logps, nullptr, V_, R_, V_, H_,
        use_stats ? stats : nullptr, NBLKV_);
  else
    k_wv_f32<<<dim3((V_+63)/64, R_/64), 256, 0, stream>>>(dec_states, W_v, b_v, logps);

  k_final2<<<R_, 512, 0, stream>>>(logps, pgens, attns, src_tokens,
                                   (fast_wv && use_stats) ? stats : nullptr, NBLKV_);
}

// Round 12
// 1134.482 us; speedup vs baseline: 1.5718x; 1.0532x over previous
//
#include <hip/hip_runtime.h>
#include <hip/hip_bf16.h>
#include <stdint.h>
#include <stddef.h>

#define B_  32
#define S_  400
#define T_  32
#define H_  512
#define E_  128
#define V_  50000
#define A_  512
#define H2_ 1024
#define H3_ 1536
#define H4_ 2048
#define R_  1024     // B*T
#define PGK_ 1664    // 3H+E
#define NBLKV_ 391   // ceil(V/128)
#define GRB_ 128     // persistent-recurrence grid
#define WROW_ 520    // u16 row stride for LDS bf16 tiles (16B-aligned)

typedef unsigned short u16;
typedef short v8s __attribute__((ext_vector_type(8)));
typedef float v4f __attribute__((ext_vector_type(4)));

__device__ __forceinline__ float fsig(float x){ return 1.0f/(1.0f + __expf(-x)); }
__device__ __forceinline__ float ftanh(float x){ float e = __expf(2.0f*x); return 1.0f - 2.0f/(e + 1.0f); }
__device__ __forceinline__ u16 f2bf(float x){ __hip_bfloat16 b = __float2bfloat16(x); return *reinterpret_cast<u16*>(&b); }
__device__ __forceinline__ float bf2f(u16 u){ __hip_bfloat16 b = *reinterpret_cast<__hip_bfloat16*>(&u); return __bfloat162float(b); }

__device__ __forceinline__ float wsum(float v){
  #pragma unroll
  for (int off = 32; off > 0; off >>= 1) v += __shfl_xor(v, off, 64);
  return v;
}
__device__ __forceinline__ float wmax(float v){
  #pragma unroll
  for (int off = 32; off > 0; off >>= 1) v = fmaxf(v, __shfl_xor(v, off, 64));
  return v;
}

#define ALD(p)    __hip_atomic_load((p), __ATOMIC_RELAXED, __HIP_MEMORY_SCOPE_AGENT)
#define AST(p,v)  __hip_atomic_store((p), (v), __ATOMIC_RELAXED, __HIP_MEMORY_SCOPE_AGENT)

// LDS-only barrier: waits lgkmcnt (LDS) but leaves vmem (prefetch) in flight.
__device__ __forceinline__ void ldsbar(){
  asm volatile("s_waitcnt lgkmcnt(0)" ::: "memory");
  __builtin_amdgcn_s_barrier();
  asm volatile("" ::: "memory");
}

// hierarchical fence-free grid barrier: 8 spread counters (16 arrivals each,
// keyed by beta&7) -> 1 global counter (8 arrivals) -> gate. Monotonic counts.
__device__ __forceinline__ void gridbar2(unsigned* bar, unsigned target, int grp){
  __syncthreads();
  if (threadIdx.x == 0){
    unsigned v = __hip_atomic_fetch_add(bar + grp*32, 1u, __ATOMIC_RELAXED, __HIP_MEMORY_SCOPE_AGENT);
    if (v == target*16u - 1u){
      unsigned g2 = __hip_atomic_fetch_add(bar + 256, 1u, __ATOMIC_RELAXED, __HIP_MEMORY_SCOPE_AGENT);
      if (g2 == target*8u - 1u)
        AST(bar + 288, target);
    }
    while (ALD(bar + 288) < target) __builtin_amdgcn_s_sleep(2);
    asm volatile("" ::: "memory");
  }
  __syncthreads();
}

// ---------------- setup kernels ----------------

__global__ void k_init0(unsigned* __restrict__ bar, unsigned long long* __restrict__ mz){
  int t = threadIdx.x;
  if (t < 512) AST(bar + t, 0u);
  if (t < 256) AST(mz + t, 0ull);
}

__global__ __launch_bounds__(256) void k_transpose(const float* __restrict__ in, float* __restrict__ out, int R, int C){
  __shared__ float tile[64][65];
  int c0 = blockIdx.x*64, r0 = blockIdx.y*64;
  int tid = threadIdx.x;
  int cl = tid & 63, q = tid >> 6;
  #pragma unroll
  for (int i=0;i<16;i++){
    int r = q + i*4;
    float v = 0.0f;
    if (r0 + r < R && c0 + cl < C) v = in[(size_t)(r0+r)*C + c0 + cl];
    tile[r][cl] = v;
  }
  __syncthreads();
  #pragma unroll
  for (int i=0;i<16;i++){
    int c = q + i*4;
    if (c0 + c < C && r0 + cl < R)
      out[(size_t)(c0+c)*R + r0 + cl] = tile[cl][c];
  }
}

// f32 [R][C] -> bf16 [C][R] (hi only; used for W_v)
__global__ __launch_bounds__(256) void k_convT(const float* __restrict__ in, u16* __restrict__ hi, int R, int C){
  __shared__ float tile[64][65];
  int c0 = blockIdx.x*64, r0 = blockIdx.y*64;
  int tid = threadIdx.x;
  int cl = tid & 63, q = tid >> 6;
  #pragma unroll
  for (int i=0;i<16;i++){
    int r = q + i*4;
    float v = 0.0f;
    if (r0 + r < R && c0 + cl < C) v = in[(size_t)(r0+r)*C + c0 + cl];
    tile[r][cl] = v;
  }
  __syncthreads();
  #pragma unroll
  for (int i=0;i<16;i++){
    int c = q + i*4;
    if (c0 + c < C && r0 + cl < R)
      hi[(size_t)(c0+c)*R + r0 + cl] = f2bf(tile[cl][c]);
  }
}

// W_enc [1024][512] f32 -> WencT3 [512][3072] bf16 rows = [hi | lo | hi]
__global__ __launch_bounds__(256) void k_convT3(const float* __restrict__ in, u16* __restrict__ out){
  __shared__ float tile[64][65];
  int c0 = blockIdx.x*64, r0 = blockIdx.y*64;   // grid (8,16)
  int tid = threadIdx.x;
  int cl = tid & 63, q = tid >> 6;
  #pragma unroll
  for (int i=0;i<16;i++){
    int r = q + i*4;
    tile[r][cl] = in[(size_t)(r0+r)*A_ + c0 + cl];
  }
  __syncthreads();
  #pragma unroll
  for (int i=0;i<16;i++){
    int c = q + i*4;
    float v = tile[cl][c];
    u16 h = f2bf(v);
    u16 lo = f2bf(v - bf2f(h));
    size_t o = (size_t)(c0+c)*3072 + (r0+cl);
    out[o] = h;
    out[o + 1024] = lo;
    out[o + 2048] = h;
  }
}

// enc [12800][1024] f32 -> enc3 [12800][3072] bf16 rows = [hi | hi | lo]
__global__ void k_conv3(const float* __restrict__ in, u16* __restrict__ out, int n4){
  int i = blockIdx.x*256 + threadIdx.x;
  if (i >= n4) return;
  float4 x = reinterpret_cast<const float4*>(in)[i];
  u16 h0v=f2bf(x.x), h1v=f2bf(x.y), h2v=f2bf(x.z), h3v=f2bf(x.w);
  uint2 hv; hv.x = (unsigned)h0v | ((unsigned)h1v << 16); hv.y = (unsigned)h2v | ((unsigned)h3v << 16);
  uint2 lv;
  lv.x = (unsigned)f2bf(x.x - bf2f(h0v)) | ((unsigned)f2bf(x.y - bf2f(h1v)) << 16);
  lv.y = (unsigned)f2bf(x.z - bf2f(h2v)) | ((unsigned)f2bf(x.w - bf2f(h3v)) << 16);
  int row = i >> 8, c = (i & 255)*4;
  size_t base = (size_t)row*3072 + c;
  *reinterpret_cast<uint2*>(out + base)        = hv;
  *reinterpret_cast<uint2*>(out + base + 1024) = hv;
  *reinterpret_cast<uint2*>(out + base + 2048) = lv;
}

// G2[t][g][hidx][b] = b_ih + b_hh + emb @ W_ih^T   (layout for k_recur coalesced reads)
__global__ __launch_bounds__(256) void k_gih(const float* __restrict__ emb, const float* __restrict__ WihT,
    const float* __restrict__ b_ih, const float* __restrict__ b_hh, float* __restrict__ G){
  __shared__ float em[8][128];
  int r0 = blockIdx.x*8;
  int tid = threadIdx.x;
  #pragma unroll
  for (int i=0;i<4;i++){
    int e = i*256 + tid;
    em[e>>7][e&127] = emb[(size_t)(r0 + (e>>7))*E_ + (e&127)];
  }
  __syncthreads();
  for (int jj=0;jj<8;jj++){
    int j = jj*256 + tid;
    float bias = b_ih[j] + b_hh[j];
    float acc[8];
    #pragma unroll
    for (int r=0;r<8;r++) acc[r] = bias;
    for (int e=0;e<128;e++){
      float wv = WihT[(size_t)e*H4_ + j];
      #pragma unroll
      for (int r=0;r<8;r++) acc[r] += em[r][e]*wv;
    }
    #pragma unroll
    for (int rr=0;rr<8;rr++){
      int r = r0 + rr;
      G[(size_t)(r & 31)*65536 + (size_t)(j >> 9)*16384 + (size_t)(j & 511)*32 + (r >> 5)] = acc[rr];
    }
  }
}

// ---------------- MFMA bf16 GEMM (coalesced LDS epilogue, optional stats) ----------------
__global__ __launch_bounds__(256, 2) void k_gemm_bf16(
    const u16* __restrict__ A, int lda, const u16* __restrict__ Bt, int ldb,
    const float* __restrict__ bias, float* __restrict__ Cf, u16* __restrict__ Cbf, int ldc,
    int M, int N, int K, float2* __restrict__ stats, int nblk)
{
  __shared__ __align__(16) float CsF[128*132];
  __shared__ float rs[128], rs2[128];
  u16* As = reinterpret_cast<u16*>(CsF);
  u16* Bs = As + 128*64;
  const int tid = threadIdx.x;
  const int m0 = blockIdx.y * 128;
  const int n0 = blockIdx.x * 128;
  const int l  = tid & 63;
  const int wavebase = tid & ~63;
  const int wid = tid >> 6;
  const int wm = (wid >> 1) * 64;
  const int wn = (wid & 1) * 64;

  v4f acc[4][4];
  v4f vzero = {0.0f, 0.0f, 0.0f, 0.0f};
  #pragma unroll
  for (int i=0;i<4;i++)
    #pragma unroll
    for (int j=0;j<4;j++) acc[i][j] = vzero;

  for (int k0 = 0; k0 < K; k0 += 64){
    __syncthreads();
    #pragma unroll
    for (int jj=0;jj<4;jj++){
      int fc = jj*256 + tid;
      int row = fc >> 3;
      int cc = (fc & 7) ^ (row & 7);
      const u16* g = A + (size_t)(m0 + row)*lda + k0 + cc*8;
      __builtin_amdgcn_global_load_lds(
        (__attribute__((address_space(1))) void*)g,
        (__attribute__((address_space(3))) void*)(As + (size_t)(jj*256 + wavebase)*8),
        16, 0, 0);
    }
    #pragma unroll
    for (int jj=0;jj<4;jj++){
      int fc = jj*256 + tid;
      int row = fc >> 3;
      int cc = (fc & 7) ^ (row & 7);
      int rn = n0 + row; if (rn > N-1) rn = N-1;
      const u16* g = Bt + (size_t)rn*ldb + k0 + cc*8;
      __builtin_amdgcn_global_load_lds(
        (__attribute__((address_space(1))) void*)g,
        (__attribute__((address_space(3))) void*)(Bs + (size_t)(jj*256 + wavebase)*8),
        16, 0, 0);
    }
    __syncthreads();
    #pragma unroll
    for (int ks=0;ks<2;ks++){
      v8s af[4], bfr[4];
      #pragma unroll
      for (int rt=0;rt<4;rt++){
        int r = wm + rt*16 + (l & 15);
        int cs = (ks*4 + (l >> 4)) ^ (r & 7);
        af[rt] = *reinterpret_cast<const v8s*>(As + r*64 + cs*8);
      }
      #pragma unroll
      for (int nt=0;nt<4;nt++){
        int r = wn + nt*16 + (l & 15);
        int cs = (ks*4 + (l >> 4)) ^ (r & 7);
        bfr[nt] = *reinterpret_cast<const v8s*>(Bs + r*64 + cs*8);
      }
      #pragma unroll
      for (int rt=0;rt<4;rt++)
        #pragma unroll
        for (int nt=0;nt<4;nt++)
          acc[rt][nt] = __builtin_amdgcn_mfma_f32_16x16x32_bf16(af[rt], bfr[nt], acc[rt][nt], 0, 0, 0);
    }
  }

  const int cl = l & 15;
  const int rg = (l >> 4) * 4;
  float cvv[4][4][4];
  #pragma unroll
  for (int rt=0;rt<4;rt++)
    #pragma unroll
    for (int nt=0;nt<4;nt++){
      int gc = n0 + wn + nt*16 + cl;
      float bv = (bias && gc < N) ? bias[gc] : 0.0f;
      #pragma unroll
      for (int i=0;i<4;i++) cvv[rt][nt][i] = acc[rt][nt][i] + bv;
    }

  if (stats){
    float tsm[4][4];
    #pragma unroll
    for (int rt=0;rt<4;rt++)
      #pragma unroll
      for (int i=0;i<4;i++){
        float mx = -1e30f;
        #pragma unroll
        for (int nt=0;nt<4;nt++){
          int gc = n0 + wn + nt*16 + cl;
          if (gc < N) mx = fmaxf(mx, cvv[rt][nt][i]);
        }
        #pragma unroll
        for (int off=1; off<16; off<<=1) mx = fmaxf(mx, __shfl_xor(mx, off, 64));
        if (wn == 0 && cl == 0) rs[wm + rt*16 + rg + i] = mx;
        tsm[rt][i] = mx;
      }
    __syncthreads();
    if (wn != 0){
      #pragma unroll
      for (int rt=0;rt<4;rt++)
        #pragma unroll
        for (int i=0;i<4;i++){
          float c = fmaxf(tsm[rt][i], rs[wm + rt*16 + rg + i]);
          if (cl == 0) rs[wm + rt*16 + rg + i] = c;
        }
    }
    __syncthreads();
    #pragma unroll
    for (int rt=0;rt<4;rt++)
      #pragma unroll
      for (int i=0;i<4;i++){
        float rm = rs[wm + rt*16 + rg + i];
        float sm = 0.0f;
        #pragma unroll
        for (int nt=0;nt<4;nt++){
          int gc = n0 + wn + nt*16 + cl;
          if (gc < N) sm += __expf(cvv[rt][nt][i] - rm);
        }
        #pragma unroll
        for (int off=1; off<16; off<<=1) sm += __shfl_xor(sm, off, 64);
        tsm[rt][i] = sm;
        if (wn == 0 && cl == 0) rs2[wm + rt*16 + rg + i] = sm;
      }
    __syncthreads();
    if (wn != 0 && cl == 0){
      #pragma unroll
      for (int rt=0;rt<4;rt++)
        #pragma unroll
        for (int i=0;i<4;i++){
          int row = wm + rt*16 + rg + i;
          stats[(size_t)(m0 + row)*nblk + blockIdx.x] =
            make_float2(rs[row], tsm[rt][i] + rs2[row]);
        }
    }
  }

  __syncthreads();
  #pragma unroll
  for (int rt=0;rt<4;rt++)
    #pragma unroll
    for (int nt=0;nt<4;nt++)
      #pragma unroll
      for (int i=0;i<4;i++)
        CsF[(wm + rt*16 + rg + i)*132 + wn + nt*16 + cl] = cvv[rt][nt][i];
  __syncthreads();
  #pragma unroll
  for (int it=0; it<16; ++it){
    int row = (tid >> 5) + it*8;
    int c4 = tid & 31;
    int gc = n0 + c4*4;
    int gr = m0 + row;
    if (gc < N){
      float4 v = *reinterpret_cast<const float4*>(&CsF[row*132 + c4*4]);
      if (Cf) *reinterpret_cast<float4*>(Cf + (size_t)gr*ldc + gc) = v;
      if (Cbf){
        uint2 o;
        o.x = (unsigned)f2bf(v.x) | ((unsigned)f2bf(v.y) << 16);
        o.y = (unsigned)f2bf(v.z) | ((unsigned)f2bf(v.w) << 16);
        *reinterpret_cast<uint2*>(Cbf + (size_t)gr*ldc + gc) = o;
      }
    }
  }
}

// fallback f32 GEMM for W_v when ws too small
__global__ __launch_bounds__(256) void k_wv_f32(
  const float* __restrict__ Aah, const float* __restrict__ Wv, const float* __restrict__ bv,
  float* __restrict__ Cl)
{
  __shared__ float Asf[32][68];
  __shared__ float Bsf[32][64];
  int n0 = blockIdx.x*64, m0 = blockIdx.y*64;
  int tid = threadIdx.x;
  int tx = tid & 15, ty = tid >> 4;
  float acc[4][4] = {};
  for (int kc = 0; kc < H_; kc += 32){
    __syncthreads();
    #pragma unroll
    for (int i=0;i<8;i++){
      int e = i*256 + tid;
      Asf[e & 31][e >> 5] = Aah[(size_t)(m0 + (e >> 5))*H_ + kc + (e & 31)];
    }
    #pragma unroll
    for (int i=0;i<8;i++){
      int e = i*256 + tid;
      int nc = n0 + (e & 63); if (nc >= V_) nc = V_-1;
      Bsf[e >> 6][e & 63] = Wv[(size_t)(kc + (e >> 6))*V_ + nc];
    }
    __syncthreads();
    #pragma unroll
    for (int k=0;k<32;k++){
      float4 a4 = *reinterpret_cast<const float4*>(&Asf[k][ty*4]);
      float4 b4 = *reinterpret_cast<const float4*>(&Bsf[k][tx*4]);
      float av[4] = {a4.x, a4.y, a4.z, a4.w};
      float bv4[4] = {b4.x, b4.y, b4.z, b4.w};
      #pragma unroll
      for (int i=0;i<4;i++)
        #pragma unroll
        for (int j=0;j<4;j++)
          acc[i][j] = __builtin_fmaf(av[i], bv4[j], acc[i][j]);
    }
  }
  #pragma unroll
  for (int i=0;i<4;i++){
    int rr = m0 + ty*4 + i;
    #pragma unroll
    for (int j=0;j<4;j++){
      int cc = n0 + tx*4 + j;
      if (cc < V_) Cl[(size_t)rr*V_ + cc] = acc[i][j] + bv[cc];
    }
  }
}

// ---------------- persistent fused recurrence (deferred softmax finish) ----------------
// iter i (0..T+1): [cvt h hi/lo] ldsbar [MFMA gates+dec; publish dec(par)]
// ldsbar [LSTM -> publish h] gridbar [prefetch h_{i+1}]
// [finish step i-2: read mz[i&1] (barrier-ordered), softmax, attn/cov]
// [scores step i-1 -> sc_l; publish mz[(i-1)&1]]. No tag-spin.
__global__ __launch_bounds__(1024) void k_recur(
  const float* __restrict__ W_hh, const float* __restrict__ G2,
  const float* __restrict__ W_decT, const u16* __restrict__ ep_bf,
  const float* __restrict__ w_cov, const float* __restrict__ v_att,
  const void* __restrict__ maskp, const float* __restrict__ h0,
  const float* __restrict__ c0, float* __restrict__ h_gT,
  float* __restrict__ dec_g, unsigned long long* __restrict__ mz,
  float* __restrict__ catbuf, float* __restrict__ attns, float* __restrict__ covs,
  unsigned* __restrict__ bar)
{
  const int beta = blockIdx.x;
  const int tid = threadIdx.x;
  __shared__ __align__(16) u16 Whi[32*WROW_];   // rows: 16 gate, 4 dec, 12 zero
  __shared__ __align__(16) u16 Wlo[32*WROW_];
  __shared__ __align__(16) u16 Hhi[32*WROW_];   // [b][k] bf16
  __shared__ __align__(16) u16 Hlo[32*WROW_];
  __shared__ float gv2[16][32];
  __shared__ float c_l[128];
  __shared__ float dec_l[512];
  __shared__ float sc_l[100];
  __shared__ float cov_l[100];
  __shared__ float smz[4][2];

  const int b32 = tid & 31;
  const int w = tid >> 6, l = tid & 63;
  const int grp = beta & 7;            // barrier arrival group
  const int bb = (beta & 7)*4 + (beta >> 5);
  const int sq = (beta >> 3) & 3;
  const int b2 = (tid & 15)*2;         // cvt/prefetch: batch pair
  const int kg = tid >> 4;             // cvt/prefetch: k-octet 0..63

  // one-time staging: W rows (16 gates + 4 dec + 12 zero) as bf16 hi/lo
  for (int idx = tid; idx < 32*512; idx += 1024){
    int row = idx >> 9;
    int k = idx & 511;
    float v = 0.0f;
    if (row < 16)      v = W_hh[((size_t)(row >> 2)*H_ + beta*4 + (row & 3))*H_ + k];
    else if (row < 20) v = W_decT[(size_t)(beta*4 + (row - 16))*H_ + k];
    u16 h = f2bf(v);
    Whi[row*WROW_ + k] = h;
    Wlo[row*WROW_ + k] = f2bf(v - bf2f(h));
  }
  if (tid < 128) c_l[tid] = c0[(size_t)(tid & 31)*H_ + beta*4 + (tid >> 5)];
  if (tid < 100) cov_l[tid] = 0.f;

  const unsigned* m32p = (const unsigned*)maskp;
  const unsigned char* m8p = (const unsigned char*)maskp;
  const bool bytemode = (m32p[0] == 0x01010101u);

  float wc8[8], va8[8];
  {
    int a0 = l*8;
    #pragma unroll
    for (int j=0;j<8;j++){ wc8[j] = w_cov[a0+j]; va8[j] = v_att[a0+j]; }
  }

  // prologue: h_state[0] from h0 ([b][k] layout)
  float hA[8], hB[8];
  unsigned long long hld[8];
  #pragma unroll
  for (int kk=0;kk<8;kk++){
    int k = kg*8 + kk;
    hA[kk] = h0[(size_t)b2*H_ + k];
    hB[kk] = h0[(size_t)(b2+1)*H_ + k];
  }

  unsigned gen = 0;
  for (int i = 0; i <= T_ + 1; ++i){
    const int par = i & 1;
    // ---- cvt h -> bf16 hi/lo, write [b][k] rows ----
    {
      v8s phA, plA, phB, plB;
      #pragma unroll
      for (int kk=0;kk<8;kk++){
        float va = hA[kk], vb = hB[kk];
        u16 ha = f2bf(va), hb = f2bf(vb);
        phA[kk] = (short)ha; plA[kk] = (short)f2bf(va - bf2f(ha));
        phB[kk] = (short)hb; plB[kk] = (short)f2bf(vb - bf2f(hb));
      }
      *reinterpret_cast<v8s*>(Hhi + (size_t)b2*WROW_ + kg*8) = phA;
      *reinterpret_cast<v8s*>(Hlo + (size_t)b2*WROW_ + kg*8) = plA;
      *reinterpret_cast<v8s*>(Hhi + (size_t)(b2+1)*WROW_ + kg*8) = phB;
      *reinterpret_cast<v8s*>(Hlo + (size_t)(b2+1)*WROW_ + kg*8) = plB;
    }
    ldsbar();

    // ---- MFMA gates+dec: D[20x32] = W · h^T, split-bf16 3 passes ----
    if (w < 4){
      const int mt = w >> 1, nt = w & 1;
      const int fr = (l & 15);
      const int fo = (l >> 4)*8;
      const u16* Ahi = Whi + (size_t)(mt*16 + fr)*WROW_ + fo;
      const u16* Alo = Wlo + (size_t)(mt*16 + fr)*WROW_ + fo;
      const u16* Bhi = Hhi + (size_t)(nt*16 + fr)*WROW_ + fo;
      const u16* Blo = Hlo + (size_t)(nt*16 + fr)*WROW_ + fo;
      v4f a0 = {0.f,0.f,0.f,0.f}, a1 = a0, a2 = a0;
      #pragma unroll
      for (int ks=0; ks<16; ks++){
        v8s wh = *reinterpret_cast<const v8s*>(Ahi + ks*32);
        v8s wl = *reinterpret_cast<const v8s*>(Alo + ks*32);
        v8s hh = *reinterpret_cast<const v8s*>(Bhi + ks*32);
        v8s hl = *reinterpret_cast<const v8s*>(Blo + ks*32);
        a0 = __builtin_amdgcn_mfma_f32_16x16x32_bf16(wh, hh, a0, 0, 0, 0);
        a1 = __builtin_amdgcn_mfma_f32_16x16x32_bf16(wh, hl, a1, 0, 0, 0);
        a2 = __builtin_amdgcn_mfma_f32_16x16x32_bf16(wl, hh, a2, 0, 0, 0);
      }
      v4f acc = a0 + a1 + a2;
      if (mt == 0){
        int col = nt*16 + fr;
        int r0w = (l >> 4)*4;
        #pragma unroll
        for (int q=0;q<4;q++) gv2[r0w + q][col] = acc[q];
      } else if ((l >> 4) == 0){
        int b = nt*16 + fr;
        float* dg = dec_g + (size_t)par*B_*A_ + (size_t)b*A_ + beta*4;
        unsigned long long p0 = ((unsigned long long)__float_as_uint(acc[1]) << 32) | __float_as_uint(acc[0]);
        unsigned long long p1 = ((unsigned long long)__float_as_uint(acc[3]) << 32) | __float_as_uint(acc[2]);
        AST(reinterpret_cast<unsigned long long*>(dg), p0);
        AST(reinterpret_cast<unsigned long long*>(dg + 2), p1);
      }
    }
    ldsbar();

    // ---- LSTM pointwise + publish h ----
    if (i < T_ && tid < 128){
      int hh = tid >> 5;
      int hidx = beta*4 + hh;
      const float* Gr = G2 + (size_t)i*65536 + (size_t)hidx*32 + b32;
      float gi = gv2[0*4+hh][b32] + Gr[0];
      float gf = gv2[1*4+hh][b32] + Gr[16384];
      float gz = gv2[2*4+hh][b32] + Gr[32768];
      float go = gv2[3*4+hh][b32] + Gr[49152];
      float co = c_l[tid];
      float cn = fsig(gf)*co + fsig(gi)*ftanh(gz);
      float hn = fsig(go)*ftanh(cn);
      c_l[tid] = cn;
      AST(h_gT + (size_t)(par^1)*16384 + (size_t)hidx*32 + b32, hn);
      catbuf[(size_t)(b32*T_ + i)*H3_ + H2_ + hidx] = hn;
    }
    gridbar2(bar, ++gen, grp);

    // ---- prefetch h_{i+1} (overlaps Y) ----
    if (i < T_){
      const unsigned long long* hp =
        reinterpret_cast<const unsigned long long*>(h_gT + (size_t)(par^1)*16384);
      #pragma unroll
      for (int kk=0;kk<8;kk++)
        hld[kk] = ALD(hp + (size_t)(kg*8 + kk)*16 + (b2 >> 1));
    }

    // ---- finish step i-2 (mz published iter i-1, ordered by gridbar) ----
    if (i >= 2){
      if (tid < 4){
        unsigned long long v = ALD(mz + (size_t)(i & 1)*128 + bb*4 + tid);
        smz[tid][0] = __uint_as_float((unsigned)v);
        smz[tid][1] = __uint_as_float((unsigned)(v >> 32));
      }
      __syncthreads();
      float gm = fmaxf(fmaxf(smz[0][0], smz[1][0]), fmaxf(smz[2][0], smz[3][0]));
      float gZ = smz[0][1]*__expf(smz[0][0]-gm) + smz[1][1]*__expf(smz[1][0]-gm)
               + smz[2][1]*__expf(smz[2][0]-gm) + smz[3][1]*__expf(smz[3][0]-gm);
      float invZ = 1.f/gZ;
      int r2 = bb*T_ + (i-2);
      if (tid < 100){
        float av = __expf(sc_l[tid] - gm)*invZ;
        int s = sq*100 + tid;
        float cn = cov_l[tid] + av;
        cov_l[tid] = cn;
        attns[(size_t)r2*S_ + s] = av;
        covs[(size_t)r2*S_ + s]  = cn;
      }
      __syncthreads();
    }

    // ---- scores step i-1; publish (m,Z) to mz[(i-1)&1] ----
    if (i >= 1 && i <= T_){
      if (tid < 512) dec_l[tid] = ALD(dec_g + (size_t)par*B_*A_ + (size_t)bb*A_ + tid);
      ldsbar();
      int a0i = l*8;
      float dec8[8];
      #pragma unroll
      for (int j=0;j<8;j++) dec8[j] = dec_l[a0i+j];
      #pragma unroll
      for (int it=0; it<7; ++it){
        int sl = w + it*16;
        if (sl < 100){
          int s = sq*100 + sl;
          float cv = cov_l[sl];
          uint4 e8 = *reinterpret_cast<const uint4*>(ep_bf + (size_t)(bb*S_ + s)*A_ + a0i);
          unsigned uu[4] = {e8.x, e8.y, e8.z, e8.w};
          float part = 0.f;
          #pragma unroll
          for (int j=0;j<4;j++){
            float xa = bf2f((u16)(uu[j] & 0xFFFFu)) + dec8[2*j]   + cv*wc8[2*j];
            part += va8[2*j]*ftanh(xa);
            float xb = bf2f((u16)(uu[j] >> 16))     + dec8[2*j+1] + cv*wc8[2*j+1];
            part += va8[2*j+1]*ftanh(xb);
          }
          part = wsum(part);
          if (l == 0){
            bool on = bytemode ? (m8p[bb*S_+s] != 0) : (m32p[bb*S_+s] != 0u);
            sc_l[sl] = on ? part : -1e9f;
          }
        }
      }
      __syncthreads();
      if (tid < 64){
        float x1v = sc_l[l];
        float x2v = (l + 64 < 100) ? sc_l[l + 64] : -1e30f;
        float m = wmax(fmaxf(x1v, x2v));
        float z = __expf(x1v - m) + ((l + 64 < 100) ? __expf(x2v - m) : 0.f);
        z = wsum(z);
        if (l == 0){
          unsigned long long pk = ((unsigned long long)__float_as_uint(z) << 32)
                                | (unsigned long long)__float_as_uint(m);
          AST(mz + (size_t)((i-1) & 1)*128 + bb*4 + sq, pk);
        }
      }
    }

    // ---- unpack prefetched h for next iteration ----
    if (i < T_){
      #pragma unroll
      for (int kk=0;kk<8;kk++){
        hA[kk] = __uint_as_float((unsigned)hld[kk]);
        hB[kk] = __uint_as_float((unsigned)(hld[kk] >> 32));
      }
    }
  }
}

// ---------------- post-loop kernels ----------------

// context (deferred): catbuf[:, :1024] = attns @ enc_hi(bf16)  (single pass)
__global__ __launch_bounds__(256, 2) void k_ctx(
  const float* __restrict__ attns, const u16* __restrict__ enc3, float* __restrict__ catbuf)
{
  __shared__ float att_s[32][400];
  int d0 = blockIdx.x*64, b = blockIdx.y;
  int tid = threadIdx.x;
  for (int tt=0; tt<32; ++tt)
    for (int s = tid; s < S_; s += 256)
      att_s[tt][s] = attns[(size_t)(b*T_ + tt)*S_ + s];
  __syncthreads();
  int lane = tid & 31;
  int d = d0 + lane*2;
  int tg = tid >> 5;                 // 8 groups x 4 t
  float acc0[4] = {0,0,0,0}, acc1[4] = {0,0,0,0};
  const u16* encb = enc3 + (size_t)(b*S_)*3072 + d;
  #pragma unroll 4
  for (int s=0; s<S_; ++s){
    unsigned uv = *reinterpret_cast<const unsigned*>(encb + (size_t)s*3072);
    float e0 = bf2f((u16)(uv & 0xFFFFu));
    float e1 = bf2f((u16)(uv >> 16));
    #pragma unroll
    for (int i=0;i<4;i++){
      float av = att_s[tg*4 + i][s];
      acc0[i] = __builtin_fmaf(av, e0, acc0[i]);
      acc1[i] = __builtin_fmaf(av, e1, acc1[i]);
    }
  }
  #pragma unroll
  for (int i=0;i<4;i++)
    *reinterpret_cast<float2*>(catbuf + (size_t)(b*T_ + tg*4 + i)*H3_ + d) =
      make_float2(acc0[i], acc1[i]);
}

// fp32 tiled GEMM: dec_states = tanh(catbuf @ W_ah + b_ah); optional bf16 copy
__global__ __launch_bounds__(256) void k_ahgemm(
  const float* __restrict__ Acat, const float* __restrict__ W_ah, const float* __restrict__ b_ah,
  float* __restrict__ dec_states, u16* __restrict__ ah_bf)
{
  __shared__ float Asf[32][68];
  __shared__ float Bsf[32][64];
  int n0 = blockIdx.x*64, m0 = blockIdx.y*64;
  int tid = threadIdx.x;
  int tx = tid & 15, ty = tid >> 4;
  float acc[4][4] = {};
  for (int kc = 0; kc < H3_; kc += 32){
    __syncthreads();
    #pragma unroll
    for (int i=0;i<8;i++){
      int e = i*256 + tid;
      Asf[e & 31][e >> 5] = Acat[(size_t)(m0 + (e >> 5))*H3_ + kc + (e & 31)];
    }
    #pragma unroll
    for (int i=0;i<8;i++){
      int e = i*256 + tid;
      Bsf[e >> 6][e & 63] = W_ah[(size_t)(kc + (e >> 6))*H_ + n0 + (e & 63)];
    }
    __syncthreads();
    #pragma unroll
    for (int k=0;k<32;k++){
      float4 a4 = *reinterpret_cast<const float4*>(&Asf[k][ty*4]);
      float4 b4 = *reinterpret_cast<const float4*>(&Bsf[k][tx*4]);
      float av[4] = {a4.x, a4.y, a4.z, a4.w};
      float bv[4] = {b4.x, b4.y, b4.z, b4.w};
      #pragma unroll
      for (int i=0;i<4;i++)
        #pragma unroll
        for (int j=0;j<4;j++)
          acc[i][j] = __builtin_fmaf(av[i], bv[j], acc[i][j]);
    }
  }
  #pragma unroll
  for (int i=0;i<4;i++){
    int rr = m0 + ty*4 + i;
    #pragma unroll
    for (int j=0;j<4;j++){
      int cc = n0 + tx*4 + j;
      float v = ftanh(acc[i][j] + b_ah[cc]);
      dec_states[(size_t)rr*H_ + cc] = v;
      if (ah_bf) ah_bf[(size_t)rr*H_ + cc] = f2bf(v);
    }
  }
}

__global__ __launch_bounds__(512) void k_pgen(const float* __restrict__ catbuf, const float* __restrict__ emb,
  const float* __restrict__ W_pg, const float* __restrict__ b_pg, float* __restrict__ pgens)
{
  int w = threadIdx.x >> 6, l = threadIdx.x & 63;
  int r = blockIdx.x*8 + w;
  float part = 0.0f;
  for (int d = l; d < PGK_; d += 64){
    float x = (d < H3_) ? catbuf[(size_t)r*H3_ + d] : emb[(size_t)r*E_ + (d - H3_)];
    part += x*W_pg[d];
  }
  part = wsum(part);
  if (l == 0) pgens[r] = fsig(part + b_pg[0]);
}

// per-row final: stats merge -> bitmask+hash scatter -> fast log transform
// rowbf != nullptr: logits were written bf16 to d_ws (saves 205 MB HBM)
__global__ __launch_bounds__(512) void k_final2(
  float* __restrict__ logits, const u16* __restrict__ rowbf,
  const float* __restrict__ pgens,
  const float* __restrict__ attns, const int* __restrict__ src,
  const float2* __restrict__ stats, int nblk)
{
  __shared__ unsigned bits[1568];
  __shared__ unsigned keys[1024];
  __shared__ float vals[1024];
  __shared__ float sred[18];
  int r = blockIdx.x;
  int b = r >> 5;
  int tid = threadIdx.x;
  int w = tid >> 6, l = tid & 63;
  float* row = logits + (size_t)r*V_;
  const u16* rb = rowbf ? (rowbf + (size_t)r*V_) : nullptr;

  for (int i = tid; i < 1568; i += 512) bits[i] = 0u;
  for (int i = tid; i < 1024; i += 512){ keys[i] = 0xFFFFFFFFu; vals[i] = 0.0f; }

  if (stats){
    float m = -1e30f, Z = 0.0f;
    if (tid < nblk){ float2 st = stats[(size_t)r*nblk + tid]; m = st.x; Z = st.y; }
    #pragma unroll
    for (int off=32; off>0; off>>=1){
      float mo = __shfl_xor(m, off, 64);
      float Zo = __shfl_xor(Z, off, 64);
      float nm = fmaxf(m, mo);
      Z = Z*__expf(m - nm) + Zo*__expf(mo - nm);
      m = nm;
    }
    if (l == 0){ sred[w*2] = m; sred[w*2+1] = Z; }
    __syncthreads();
    if (tid == 0){
      float gm = -1e30f, gz = 0.0f;
      #pragma unroll
      for (int i=0;i<8;i++){
        float mi = sred[i*2], zi = sred[i*2+1];
        float nm = fmaxf(gm, mi);
        gz = gz*__expf(gm - nm) + zi*__expf(mi - nm);
        gm = nm;
      }
      sred[16] = gm; sred[17] = gz;
    }
    __syncthreads();
  } else {
    float m = -1e30f;
    for (int j = tid; j < V_/4; j += 512){
      float4 x = reinterpret_cast<const float4*>(row)[j];
      m = fmaxf(fmaxf(m, x.x), fmaxf(fmaxf(x.y, x.z), x.w));
    }
    m = wmax(m);
    if (l == 0) sred[w] = m;
    __syncthreads();
    if (tid == 0){
      float gm = -1e30f;
      #pragma unroll
      for (int i=0;i<8;i++) gm = fmaxf(gm, sred[i]);
      sred[16] = gm;
    }
    __syncthreads();
    float gm = sred[16];
    float z = 0.0f;
    for (int j = tid; j < V_/4; j += 512){
      float4 x = reinterpret_cast<const float4*>(row)[j];
      z += __expf(x.x-gm) + __expf(x.y-gm) + __expf(x.z-gm) + __expf(x.w-gm);
    }
    z = wsum(z);
    if (l == 0) sred[8 + w] = z;
    __syncthreads();
    if (tid == 0){
      float gz = 0.0f;
      #pragma unroll
      for (int i=0;i<8;i++) gz += sred[8 + i];
      sred[17] = gz;
    }
    __syncthreads();
  }

  float gm = sred[16];
  float gZ = sred[17];
  float pg = pgens[r];
  float scale = pg / gZ;
  float lscale = __logf(scale);

  if (tid < S_){
    int tok = src[b*S_ + tid];
    float add = (1.0f - pg)*attns[(size_t)r*S_ + tid];
    atomicOr(&bits[tok >> 5], 1u << (tok & 31));
    unsigned h = ((unsigned)tok * 2654435761u) >> 22;
    while (true){
      unsigned prev = atomicCAS(&keys[h], 0xFFFFFFFFu, (unsigned)tok);
      if (prev == 0xFFFFFFFFu || prev == (unsigned)tok){
        atomicAdd(&vals[h], add);
        break;
      }
      h = (h + 1) & 1023;
    }
  }
  __syncthreads();

  for (int j = tid; j < V_/4; j += 512){
    float xv[4];
    if (rb){
      uint2 u = reinterpret_cast<const uint2*>(rb)[j];
      xv[0] = bf2f((u16)(u.x & 0xFFFFu)); xv[1] = bf2f((u16)(u.x >> 16));
      xv[2] = bf2f((u16)(u.y & 0xFFFFu)); xv[3] = bf2f((u16)(u.y >> 16));
    } else {
      float4 x = reinterpret_cast<const float4*>(row)[j];
      xv[0] = x.x; xv[1] = x.y; xv[2] = x.z; xv[3] = x.w;
    }
    int v = 4*j;
    float o[4];
    #pragma unroll
    for (int k=0;k<4;k++){
      int vv = v + k;
      bool hit = (bits[vv >> 5] >> (vv & 31)) & 1u;
      float tt = xv[k] - gm + lscale;
      if (!hit && tt > -25.0f){
        o[k] = tt;
      } else {
        float pval = __expf(xv[k] - gm)*scale;
        if (hit){
          unsigned h = ((unsigned)vv * 2654435761u) >> 22;
          while (keys[h] != 0xFFFFFFFFu){
            if (keys[h] == (unsigned)vv){ pval += vals[h]; break; }
            h = (h + 1) & 1023;
          }
        }
        o[k] = __logf(pval + 1e-20f);
      }
    }
    reinterpret_cast<float4*>(row)[j] = make_float4(o[0], o[1], o[2], o[3]);
  }
}

// ---------------- host ----------------

extern "C" void kernel_launch(void* const* d_in, const int* in_sizes, int n_in,
                              void* d_out, int out_size, void* d_ws, size_t ws_size,
                              hipStream_t stream)
{
  const int* src_tokens = (const int*)d_in[0];
  const float* embedded = (const float*)d_in[1];
  const float* enc      = (const float*)d_in[2];
  const void*  maskp    = (const void*)d_in[3];
  const float* h0  = (const float*)d_in[4];
  const float* c0  = (const float*)d_in[5];
  const float* W_ih = (const float*)d_in[6];
  const float* W_hh = (const float*)d_in[7];
  const float* b_ih = (const float*)d_in[8];
  const float* b_hh = (const float*)d_in[9];
  const float* W_enc = (const float*)d_in[10];
  const float* W_dec = (const float*)d_in[11];
  const float* w_cov = (const float*)d_in[12];
  const float* b_att = (const float*)d_in[13];
  const float* v_att = (const float*)d_in[14];
  const float* W_ah  = (const float*)d_in[15];
  const float* b_ah  = (const float*)d_in[16];
  const float* W_pg  = (const float*)d_in[17];
  const float* b_pg  = (const float*)d_in[18];
  const float* W_v   = (const float*)d_in[19];
  const float* b_v   = (const float*)d_in[20];
  (void)in_sizes; (void)n_in; (void)out_size;

  float* outp = (float*)d_out;
  float* logps = outp;                                  // (B,T,V)   204.8 MB
  float* dec_states = logps + (size_t)R_*V_;            // (B,T,H)
  float* attns = dec_states + (size_t)R_*H_;            // (B,T,S)
  float* covs  = attns + (size_t)R_*S_;                 // (B,T,S)
  float* pgens = covs + (size_t)R_*S_;                  // (B,T)

  // big transients live INSIDE the logps output region (dead until W_v GEMM)
  char* sp = (char*)logps;
  auto salloc = [&](size_t bytes) -> void* {
    void* p = (void*)sp;
    sp += (bytes + 255) & ~(size_t)255;
    return p;
  };
  unsigned* bar = (unsigned*)salloc(2048);
  unsigned long long* mz = (unsigned long long*)salloc((size_t)2*B_*4*8);
  u16* ep_bf    = (u16*)salloc((size_t)B_*S_*A_*2);        // 13.1 MB
  u16* enc3     = (u16*)salloc((size_t)B_*S_*3072*2);      // 78.6 MB
  u16* WencT3   = (u16*)salloc((size_t)A_*3072*2);         // 3.1 MB
  float* WihT   = (float*)salloc((size_t)E_*H4_*4);        // 1 MB
  float* W_decT = (float*)salloc((size_t)H_*A_*4);         // 1 MB
  float* G2     = (float*)salloc((size_t)R_*H4_*4);        // 8.4 MB [t][g][hidx][b]
  float* catbuf = (float*)salloc((size_t)R_*H3_*4);        // 6.3 MB [context | h]
  float* dec_g  = (float*)salloc((size_t)2*B_*A_*4);       // 128 KB double-buffered
  float* h_gT   = (float*)salloc((size_t)2*H_*B_*4);       // 128 KB double-buffered [k][b]
  // total ~112 MB < 204.8 MB -- all consumed before W_v GEMM writes logps

  // d_ws: only buffers live WHILE logps is being written
  char* wp = (char*)d_ws;
  auto walloc = [&](size_t bytes) -> void* {
    void* p = (void*)wp;
    wp += (bytes + 255) & ~(size_t)255;
    return p;
  };
  u16* ah_bf = (u16*)walloc((size_t)R_*H_*2);              // 1.05 MB
  u16* WvT   = (u16*)walloc((size_t)V_*H_*2);              // 51.2 MB
  float2* stats = (float2*)walloc((size_t)R_*NBLKV_*8);    // 3.2 MB
  u16* logits_bf = (u16*)walloc((size_t)R_*V_*2);          // 102.4 MB (optional tier)
  const size_t ws_fast  = (size_t)R_*H_*2 + (size_t)V_*H_*2 + 512;
  const size_t ws_stats = ws_fast + (size_t)R_*NBLKV_*8 + 256;
  const size_t ws_bf    = ws_stats + (size_t)R_*V_*2 + 256;
  const bool fast_wv   = (ws_size >= ws_fast);
  const bool use_stats = (ws_size >= ws_stats);
  const bool use_bf    = (ws_size >= ws_bf) && use_stats;

  // setup
  k_init0<<<1, 512, 0, stream>>>(bar, mz);
  k_transpose<<<dim3(2,32), 256, 0, stream>>>(W_ih, WihT, H4_, E_);
  k_transpose<<<dim3(8,8), 256, 0, stream>>>(W_dec, W_decT, H_, A_);
  k_gih<<<128, 256, 0, stream>>>(embedded, WihT, b_ih, b_hh, G2);
  k_conv3<<<(B_*S_*H2_/4 + 255)/256, 256, 0, stream>>>(enc, enc3, B_*S_*H2_/4);
  k_convT3<<<dim3(8,16), 256, 0, stream>>>(W_enc, WencT3);
  if (fast_wv)
    k_convT<<<dim3((V_+63)/64, 8), 256, 0, stream>>>(W_v, WvT, H_, V_);

  // enc_proj: single split-bf16 GEMM (K=3072), bf16 output + b_att
  k_gemm_bf16<<<dim3(A_/128, (B_*S_)/128), 256, 0, stream>>>(
      enc3, 3072, WencT3, 3072, b_att, nullptr, ep_bf, A_, B_*S_, A_, 3072, nullptr, 0);

  // fused persistent recurrence (deferred-softmax, 34 barriers)
  k_recur<<<GRB_, 1024, 0, stream>>>(W_hh, G2, W_decT, ep_bf, w_cov, v_att, maskp,
                                     h0, c0, h_gT, dec_g, mz,
                                     catbuf, attns, covs, bar);

  // deferred contexts + batched tail
  k_ctx<<<dim3(16, 32), 256, 0, stream>>>(attns, enc3, catbuf);
  k_ahgemm<<<dim3(8,16), 256, 0, stream>>>(catbuf, W_ah, b_ah, dec_states, fast_wv ? ah_bf : (u16*)nullptr);
  k_pgen<<<128, 512, 0, stream>>>(catbuf, embedded, W_pg, b_pg, pgens);

  // logits
  if (fast_wv)
    k_gemm_bf16<<<dim3(NBLKV_, R_/128), 256, 0, stream>>>(
        ah_bf, H_, WvT, H_, b_v,
        use_bf ? nullptr : logps, use_bf ? logits_bf : nullptr, V_,
        R_, V_, H_, use_stats ? stats : nullptr, NBLKV_);
  else
    k_wv_f32<<<dim3((V_+63)/64, R_/64), 256, 0, stream>>>(dec_states, W_v, b_v, logps);

  k_final2<<<R_, 512, 0, stream>>>(logps, use_bf ? logits_bf : (u16*)nullptr,
                                   pgens, attns, src_tokens,
                                   (fast_wv && use_stats) ? stats : nullptr, NBLKV_);
}

// Round 14
// 1066.393 us; speedup vs baseline: 1.6722x; 1.0639x over previous
//
#include <hip/hip_runtime.h>
#include <hip/hip_bf16.h>
#include <stdint.h>
#include <stddef.h>

#define B_  32
#define S_  400
#define T_  32
#define H_  512
#define E_  128
#define V_  50000
#define A_  512
#define H2_ 1024
#define H3_ 1536
#define H4_ 2048
#define R_  1024     // B*T
#define PGK_ 1664    // 3H+E
#define NBLKV_ 391   // ceil(V/128)
#define GRB_ 128     // persistent-recurrence blocks (barrier participants)
#define NCTI_ 6256   // WvT transpose tiles: ceil(V/64)*8 = 782*8
#define GRBX_ (GRB_ + (NCTI_+3)/4)   // + worker blocks (4 tiles each)
#define WROW_ 520    // u16 row stride for LDS bf16 tiles (16B-aligned)

typedef unsigned short u16;
typedef short v8s __attribute__((ext_vector_type(8)));
typedef float v4f __attribute__((ext_vector_type(4)));

__device__ __forceinline__ float fsig(float x){ return 1.0f/(1.0f + __expf(-x)); }
__device__ __forceinline__ float ftanh(float x){ float e = __expf(2.0f*x); return 1.0f - 2.0f/(e + 1.0f); }
__device__ __forceinline__ u16 f2bf(float x){ __hip_bfloat16 b = __float2bfloat16(x); return *reinterpret_cast<u16*>(&b); }
__device__ __forceinline__ float bf2f(u16 u){ __hip_bfloat16 b = *reinterpret_cast<__hip_bfloat16*>(&u); return __bfloat162float(b); }

__device__ __forceinline__ float wsum(float v){
  #pragma unroll
  for (int off = 32; off > 0; off >>= 1) v += __shfl_xor(v, off, 64);
  return v;
}
__device__ __forceinline__ float wmax(float v){
  #pragma unroll
  for (int off = 32; off > 0; off >>= 1) v = fmaxf(v, __shfl_xor(v, off, 64));
  return v;
}

#define ALD(p)    __hip_atomic_load((p), __ATOMIC_RELAXED, __HIP_MEMORY_SCOPE_AGENT)
#define AST(p,v)  __hip_atomic_store((p), (v), __ATOMIC_RELAXED, __HIP_MEMORY_SCOPE_AGENT)

// LDS-only barrier: waits lgkmcnt (LDS) but leaves vmem (prefetch) in flight.
__device__ __forceinline__ void ldsbar(){
  asm volatile("s_waitcnt lgkmcnt(0)" ::: "memory");
  __builtin_amdgcn_s_barrier();
  asm volatile("" ::: "memory");
}

// hierarchical fence-free grid barrier over GRB_ blocks: 8 spread counters
// (16 arrivals each, keyed by beta&7) -> 1 global counter (8) -> gate.
__device__ __forceinline__ void gridbar2(unsigned* bar, unsigned target, int grp){
  __syncthreads();
  if (threadIdx.x == 0){
    unsigned v = __hip_atomic_fetch_add(bar + grp*32, 1u, __ATOMIC_RELAXED, __HIP_MEMORY_SCOPE_AGENT);
    if (v == target*16u - 1u){
      unsigned g2 = __hip_atomic_fetch_add(bar + 256, 1u, __ATOMIC_RELAXED, __HIP_MEMORY_SCOPE_AGENT);
      if (g2 == target*8u - 1u)
        AST(bar + 288, target);
    }
    while (ALD(bar + 288) < target) __builtin_amdgcn_s_sleep(2);
    asm volatile("" ::: "memory");
  }
  __syncthreads();
}

// ---------------- setup kernels ----------------

__global__ void k_init0(unsigned* __restrict__ bar, unsigned long long* __restrict__ mz){
  int t = threadIdx.x;
  if (t < 512) AST(bar + t, 0u);
  if (t < 256) AST(mz + t, 0ull);
}

// W_enc [1024][512] f32 -> WencT3 [512][3072] bf16 rows = [hi | lo | hi]
__global__ __launch_bounds__(256) void k_convT3(const float* __restrict__ in, u16* __restrict__ out){
  __shared__ float tile[64][65];
  int c0 = blockIdx.x*64, r0 = blockIdx.y*64;   // grid (8,16)
  int tid = threadIdx.x;
  int cl = tid & 63, q = tid >> 6;
  #pragma unroll
  for (int i=0;i<16;i++){
    int r = q + i*4;
    tile[r][cl] = in[(size_t)(r0+r)*A_ + c0 + cl];
  }
  __syncthreads();
  #pragma unroll
  for (int i=0;i<16;i++){
    int c = q + i*4;
    float v = tile[cl][c];
    u16 h = f2bf(v);
    u16 lo = f2bf(v - bf2f(h));
    size_t o = (size_t)(c0+c)*3072 + (r0+cl);
    out[o] = h;
    out[o + 1024] = lo;
    out[o + 2048] = h;
  }
}

// enc [12800][1024] f32 -> enc3 [12800][3072] bf16 rows = [hi | hi | lo]
__global__ void k_conv3(const float* __restrict__ in, u16* __restrict__ out, int n4){
  int i = blockIdx.x*256 + threadIdx.x;
  if (i >= n4) return;
  float4 x = reinterpret_cast<const float4*>(in)[i];
  u16 h0v=f2bf(x.x), h1v=f2bf(x.y), h2v=f2bf(x.z), h3v=f2bf(x.w);
  uint2 hv; hv.x = (unsigned)h0v | ((unsigned)h1v << 16); hv.y = (unsigned)h2v | ((unsigned)h3v << 16);
  uint2 lv;
  lv.x = (unsigned)f2bf(x.x - bf2f(h0v)) | ((unsigned)f2bf(x.y - bf2f(h1v)) << 16);
  lv.y = (unsigned)f2bf(x.z - bf2f(h2v)) | ((unsigned)f2bf(x.w - bf2f(h3v)) << 16);
  int row = i >> 8, c = (i & 255)*4;
  size_t base = (size_t)row*3072 + c;
  *reinterpret_cast<uint2*>(out + base)        = hv;
  *reinterpret_cast<uint2*>(out + base + 1024) = hv;
  *reinterpret_cast<uint2*>(out + base + 2048) = lv;
}

// G2[t][g][hidx][b] = b_ih + b_hh + emb @ W_ih^T   (reads W_ih rows directly)
__global__ __launch_bounds__(256) void k_gih(const float* __restrict__ emb, const float* __restrict__ W_ih,
    const float* __restrict__ b_ih, const float* __restrict__ b_hh, float* __restrict__ G){
  __shared__ float em[8][128];
  int r0 = blockIdx.x*8;
  int tid = threadIdx.x;
  #pragma unroll
  for (int i=0;i<4;i++){
    int e = i*256 + tid;
    em[e>>7][e&127] = emb[(size_t)(r0 + (e>>7))*E_ + (e&127)];
  }
  __syncthreads();
  for (int jj=0;jj<8;jj++){
    int j = jj*256 + tid;
    float bias = b_ih[j] + b_hh[j];
    float acc[8];
    #pragma unroll
    for (int r=0;r<8;r++) acc[r] = bias;
    const float* wrow = W_ih + (size_t)j*E_;
    for (int e=0;e<128;e++){
      float wv = wrow[e];
      #pragma unroll
      for (int r=0;r<8;r++) acc[r] += em[r][e]*wv;
    }
    #pragma unroll
    for (int rr=0;rr<8;rr++){
      int r = r0 + rr;
      G[(size_t)(r & 31)*65536 + (size_t)(j >> 9)*16384 + (size_t)(j & 511)*32 + (r >> 5)] = acc[rr];
    }
  }
}

// ---------------- MFMA bf16 GEMM (coalesced LDS epilogue, optional stats) ----------------
__global__ __launch_bounds__(256, 2) void k_gemm_bf16(
    const u16* __restrict__ A, int lda, const u16* __restrict__ Bt, int ldb,
    const float* __restrict__ bias, float* __restrict__ Cf, u16* __restrict__ Cbf, int ldc,
    int M, int N, int K, float2* __restrict__ stats, int nblk)
{
  __shared__ __align__(16) float CsF[128*132];
  __shared__ float rs[128], rs2[128];
  u16* As = reinterpret_cast<u16*>(CsF);
  u16* Bs = As + 128*64;
  const int tid = threadIdx.x;
  const int m0 = blockIdx.y * 128;
  const int n0 = blockIdx.x * 128;
  const int l  = tid & 63;
  const int wavebase = tid & ~63;
  const int wid = tid >> 6;
  const int wm = (wid >> 1) * 64;
  const int wn = (wid & 1) * 64;

  v4f acc[4][4];
  v4f vzero = {0.0f, 0.0f, 0.0f, 0.0f};
  #pragma unroll
  for (int i=0;i<4;i++)
    #pragma unroll
    for (int j=0;j<4;j++) acc[i][j] = vzero;

  for (int k0 = 0; k0 < K; k0 += 64){
    __syncthreads();
    #pragma unroll
    for (int jj=0;jj<4;jj++){
      int fc = jj*256 + tid;
      int row = fc >> 3;
      int cc = (fc & 7) ^ (row & 7);
      const u16* g = A + (size_t)(m0 + row)*lda + k0 + cc*8;
      __builtin_amdgcn_global_load_lds(
        (__attribute__((address_space(1))) void*)g,
        (__attribute__((address_space(3))) void*)(As + (size_t)(jj*256 + wavebase)*8),
        16, 0, 0);
    }
    #pragma unroll
    for (int jj=0;jj<4;jj++){
      int fc = jj*256 + tid;
      int row = fc >> 3;
      int cc = (fc & 7) ^ (row & 7);
      int rn = n0 + row; if (rn > N-1) rn = N-1;
      const u16* g = Bt + (size_t)rn*ldb + k0 + cc*8;
      __builtin_amdgcn_global_load_lds(
        (__attribute__((address_space(1))) void*)g,
        (__attribute__((address_space(3))) void*)(Bs + (size_t)(jj*256 + wavebase)*8),
        16, 0, 0);
    }
    __syncthreads();
    #pragma unroll
    for (int ks=0;ks<2;ks++){
      v8s af[4], bfr[4];
      #pragma unroll
      for (int rt=0;rt<4;rt++){
        int r = wm + rt*16 + (l & 15);
        int cs = (ks*4 + (l >> 4)) ^ (r & 7);
        af[rt] = *reinterpret_cast<const v8s*>(As + r*64 + cs*8);
      }
      #pragma unroll
      for (int nt=0;nt<4;nt++){
        int r = wn + nt*16 + (l & 15);
        int cs = (ks*4 + (l >> 4)) ^ (r & 7);
        bfr[nt] = *reinterpret_cast<const v8s*>(Bs + r*64 + cs*8);
      }
      #pragma unroll
      for (int rt=0;rt<4;rt++)
        #pragma unroll
        for (int nt=0;nt<4;nt++)
          acc[rt][nt] = __builtin_amdgcn_mfma_f32_16x16x32_bf16(af[rt], bfr[nt], acc[rt][nt], 0, 0, 0);
    }
  }

  const int cl = l & 15;
  const int rg = (l >> 4) * 4;
  float cvv[4][4][4];
  #pragma unroll
  for (int rt=0;rt<4;rt++)
    #pragma unroll
    for (int nt=0;nt<4;nt++){
      int gc = n0 + wn + nt*16 + cl;
      float bv = (bias && gc < N) ? bias[gc] : 0.0f;
      #pragma unroll
      for (int i=0;i<4;i++) cvv[rt][nt][i] = acc[rt][nt][i] + bv;
    }

  if (stats){
    float tsm[4][4];
    #pragma unroll
    for (int rt=0;rt<4;rt++)
      #pragma unroll
      for (int i=0;i<4;i++){
        float mx = -1e30f;
        #pragma unroll
        for (int nt=0;nt<4;nt++){
          int gc = n0 + wn + nt*16 + cl;
          if (gc < N) mx = fmaxf(mx, cvv[rt][nt][i]);
        }
        #pragma unroll
        for (int off=1; off<16; off<<=1) mx = fmaxf(mx, __shfl_xor(mx, off, 64));
        if (wn == 0 && cl == 0) rs[wm + rt*16 + rg + i] = mx;
        tsm[rt][i] = mx;
      }
    __syncthreads();
    if (wn != 0){
      #pragma unroll
      for (int rt=0;rt<4;rt++)
        #pragma unroll
        for (int i=0;i<4;i++){
          float c = fmaxf(tsm[rt][i], rs[wm + rt*16 + rg + i]);
          if (cl == 0) rs[wm + rt*16 + rg + i] = c;
        }
    }
    __syncthreads();
    #pragma unroll
    for (int rt=0;rt<4;rt++)
      #pragma unroll
      for (int i=0;i<4;i++){
        float rm = rs[wm + rt*16 + rg + i];
        float sm = 0.0f;
        #pragma unroll
        for (int nt=0;nt<4;nt++){
          int gc = n0 + wn + nt*16 + cl;
          if (gc < N) sm += __expf(cvv[rt][nt][i] - rm);
        }
        #pragma unroll
        for (int off=1; off<16; off<<=1) sm += __shfl_xor(sm, off, 64);
        tsm[rt][i] = sm;
        if (wn == 0 && cl == 0) rs2[wm + rt*16 + rg + i] = sm;
      }
    __syncthreads();
    if (wn != 0 && cl == 0){
      #pragma unroll
      for (int rt=0;rt<4;rt++)
        #pragma unroll
        for (int i=0;i<4;i++){
          int row = wm + rt*16 + rg + i;
          stats[(size_t)(m0 + row)*nblk + blockIdx.x] =
            make_float2(rs[row], tsm[rt][i] + rs2[row]);
        }
    }
  }

  __syncthreads();
  #pragma unroll
  for (int rt=0;rt<4;rt++)
    #pragma unroll
    for (int nt=0;nt<4;nt++)
      #pragma unroll
      for (int i=0;i<4;i++)
        CsF[(wm + rt*16 + rg + i)*132 + wn + nt*16 + cl] = cvv[rt][nt][i];
  __syncthreads();
  #pragma unroll
  for (int it=0; it<16; ++it){
    int row = (tid >> 5) + it*8;
    int c4 = tid & 31;
    int gc = n0 + c4*4;
    int gr = m0 + row;
    if (gc < N){
      float4 v = *reinterpret_cast<const float4*>(&CsF[row*132 + c4*4]);
      if (Cf) *reinterpret_cast<float4*>(Cf + (size_t)gr*ldc + gc) = v;
      if (Cbf){
        uint2 o;
        o.x = (unsigned)f2bf(v.x) | ((unsigned)f2bf(v.y) << 16);
        o.y = (unsigned)f2bf(v.z) | ((unsigned)f2bf(v.w) << 16);
        *reinterpret_cast<uint2*>(Cbf + (size_t)gr*ldc + gc) = o;
      }
    }
  }
}

// fallback f32 GEMM for W_v when ws too small
__global__ __launch_bounds__(256) void k_wv_f32(
  const float* __restrict__ Aah, const float* __restrict__ Wv, const float* __restrict__ bv,
  float* __restrict__ Cl)
{
  __shared__ float Asf[32][68];
  __shared__ float Bsf[32][64];
  int n0 = blockIdx.x*64, m0 = blockIdx.y*64;
  int tid = threadIdx.x;
  int tx = tid & 15, ty = tid >> 4;
  float acc[4][4] = {};
  for (int kc = 0; kc < H_; kc += 32){
    __syncthreads();
    #pragma unroll
    for (int i=0;i<8;i++){
      int e = i*256 + tid;
      Asf[e & 31][e >> 5] = Aah[(size_t)(m0 + (e >> 5))*H_ + kc + (e & 31)];
    }
    #pragma unroll
    for (int i=0;i<8;i++){
      int e = i*256 + tid;
      int nc = n0 + (e & 63); if (nc >= V_) nc = V_-1;
      Bsf[e >> 6][e & 63] = Wv[(size_t)(kc + (e >> 6))*V_ + nc];
    }
    __syncthreads();
    #pragma unroll
    for (int k=0;k<32;k++){
      float4 a4 = *reinterpret_cast<const float4*>(&Asf[k][ty*4]);
      float4 b4 = *reinterpret_cast<const float4*>(&Bsf[k][tx*4]);
      float av[4] = {a4.x, a4.y, a4.z, a4.w};
      float bv4[4] = {b4.x, b4.y, b4.z, b4.w};
      #pragma unroll
      for (int i=0;i<4;i++)
        #pragma unroll
        for (int j=0;j<4;j++)
          acc[i][j] = __builtin_fmaf(av[i], bv4[j], acc[i][j]);
    }
  }
  #pragma unroll
  for (int i=0;i<4;i++){
    int rr = m0 + ty*4 + i;
    #pragma unroll
    for (int j=0;j<4;j++){
      int cc = n0 + tx*4 + j;
      if (cc < V_) Cl[(size_t)rr*V_ + cc] = acc[i][j] + bv[cc];
    }
  }
}

// ---------------- persistent fused recurrence + co-scheduled WvT transpose ----------------
// blocks 0..127: recurrence (deferred softmax, r12 proven).
// blocks >=128: independent workers transposing W_v f32 -> WvT bf16 (4 tiles each);
//               no barrier participation; run on the otherwise-idle 128 CUs.
__global__ __launch_bounds__(1024) void k_recur(
  const float* __restrict__ W_hh, const float* __restrict__ G2,
  const float* __restrict__ W_dec, const u16* __restrict__ ep_bf,
  const float* __restrict__ w_cov, const float* __restrict__ v_att,
  const void* __restrict__ maskp, const float* __restrict__ h0,
  const float* __restrict__ c0, float* __restrict__ h_gT,
  float* __restrict__ dec_g, unsigned long long* __restrict__ mz,
  float* __restrict__ catbuf, float* __restrict__ attns, float* __restrict__ covs,
  unsigned* __restrict__ bar,
  const float* __restrict__ Wv, u16* __restrict__ WvT)
{
  const int beta = blockIdx.x;
  const int tid = threadIdx.x;
  __shared__ __align__(16) u16 Whi[32*WROW_];   // rows: 16 gate, 4 dec, 12 zero
  __shared__ __align__(16) u16 Wlo[32*WROW_];
  __shared__ __align__(16) u16 Hhi[32*WROW_];   // [b][k] bf16
  __shared__ __align__(16) u16 Hlo[32*WROW_];
  __shared__ float gv2[16][32];
  __shared__ float c_l[128];
  __shared__ float dec_l[512];
  __shared__ float sc_l[100];
  __shared__ float cov_l[100];
  __shared__ float smz[4][2];

  if (beta >= GRB_){
    // ---- worker: WvT transpose, 4 tiles (64x64) per block ----
    // scratch: each u16[32*520] array (16640 u16) holds two 64x65 f32 tiles (8320 u16 each)
    if (WvT){
      int sub = tid >> 8;          // 0..3
      int t256 = tid & 255;
      int tix = (beta - GRB_)*4 + sub;
      int cl = t256 & 63, q = t256 >> 6;
      bool act = (tix < NCTI_);
      int txi = act ? (tix % 782) : 0;
      int tyi = act ? (tix / 782) : 0;
      int c0 = txi*64, r0 = tyi*64;
      u16* baseu = (sub & 2) ? Hhi : Whi;
      float* tile = reinterpret_cast<float*>(baseu + (sub & 1)*8320);
      if (act){
        #pragma unroll
        for (int i2=0;i2<16;i2++){
          int rr = q + i2*4;
          float v = 0.0f;
          if (c0 + cl < V_) v = Wv[(size_t)(r0+rr)*V_ + c0 + cl];
          tile[rr*65 + cl] = v;
        }
      }
      __syncthreads();
      if (act){
        #pragma unroll
        for (int i2=0;i2<16;i2++){
          int cc = q + i2*4;
          if (c0 + cc < V_)
            WvT[(size_t)(c0+cc)*H_ + r0 + cl] = f2bf(tile[cl*65 + cc]);
        }
      }
    }
    return;
  }

  const int b32 = tid & 31;
  const int w = tid >> 6, l = tid & 63;
  const int grp = beta & 7;            // barrier arrival group
  const int bb = (beta & 7)*4 + (beta >> 5);
  const int sq = (beta >> 3) & 3;
  const int b2 = (tid & 15)*2;         // cvt/prefetch: batch pair
  const int kg = tid >> 4;             // cvt/prefetch: k-octet 0..63

  // one-time staging: W rows (16 gates + 4 dec + 12 zero) as bf16 hi/lo
  for (int idx = tid; idx < 32*512; idx += 1024){
    int row = idx >> 9;
    int k = idx & 511;
    float v = 0.0f;
    if (row < 16)      v = W_hh[((size_t)(row >> 2)*H_ + beta*4 + (row & 3))*H_ + k];
    else if (row < 20) v = W_dec[(size_t)k*A_ + beta*4 + (row - 16)];
    u16 h = f2bf(v);
    Whi[row*WROW_ + k] = h;
    Wlo[row*WROW_ + k] = f2bf(v - bf2f(h));
  }
  if (tid < 128) c_l[tid] = c0[(size_t)(tid & 31)*H_ + beta*4 + (tid >> 5)];
  if (tid < 100) cov_l[tid] = 0.f;

  const unsigned* m32p = (const unsigned*)maskp;
  const unsigned char* m8p = (const unsigned char*)maskp;
  const bool bytemode = (m32p[0] == 0x01010101u);

  float wc8[8], va8[8];
  {
    int a0 = l*8;
    #pragma unroll
    for (int j=0;j<8;j++){ wc8[j] = w_cov[a0+j]; va8[j] = v_att[a0+j]; }
  }

  // prologue: h_state[0] from h0 ([b][k] layout)
  float hA[8], hB[8];
  unsigned long long hld[8];
  #pragma unroll
  for (int kk=0;kk<8;kk++){
    int k = kg*8 + kk;
    hA[kk] = h0[(size_t)b2*H_ + k];
    hB[kk] = h0[(size_t)(b2+1)*H_ + k];
  }

  unsigned gen = 0;
  for (int i = 0; i <= T_ + 1; ++i){
    const int par = i & 1;
    // ---- cvt h -> bf16 hi/lo, write [b][k] rows ----
    {
      v8s phA, plA, phB, plB;
      #pragma unroll
      for (int kk=0;kk<8;kk++){
        float va = hA[kk], vb = hB[kk];
        u16 ha = f2bf(va), hb = f2bf(vb);
        phA[kk] = (short)ha; plA[kk] = (short)f2bf(va - bf2f(ha));
        phB[kk] = (short)hb; plB[kk] = (short)f2bf(vb - bf2f(hb));
      }
      *reinterpret_cast<v8s*>(Hhi + (size_t)b2*WROW_ + kg*8) = phA;
      *reinterpret_cast<v8s*>(Hlo + (size_t)b2*WROW_ + kg*8) = plA;
      *reinterpret_cast<v8s*>(Hhi + (size_t)(b2+1)*WROW_ + kg*8) = phB;
      *reinterpret_cast<v8s*>(Hlo + (size_t)(b2+1)*WROW_ + kg*8) = plB;
    }
    ldsbar();

    // ---- MFMA gates+dec: D[20x32] = W · h^T, split-bf16 3 passes ----
    if (w < 4){
      const int mt = w >> 1, nt = w & 1;
      const int fr = (l & 15);
      const int fo = (l >> 4)*8;
      const u16* Ahi = Whi + (size_t)(mt*16 + fr)*WROW_ + fo;
      const u16* Alo = Wlo + (size_t)(mt*16 + fr)*WROW_ + fo;
      const u16* Bhi = Hhi + (size_t)(nt*16 + fr)*WROW_ + fo;
      const u16* Blo = Hlo + (size_t)(nt*16 + fr)*WROW_ + fo;
      v4f a0 = {0.f,0.f,0.f,0.f}, a1 = a0, a2 = a0;
      #pragma unroll
      for (int ks=0; ks<16; ks++){
        v8s wh = *reinterpret_cast<const v8s*>(Ahi + ks*32);
        v8s wl = *reinterpret_cast<const v8s*>(Alo + ks*32);
        v8s hh = *reinterpret_cast<const v8s*>(Bhi + ks*32);
        v8s hl = *reinterpret_cast<const v8s*>(Blo + ks*32);
        a0 = __builtin_amdgcn_mfma_f32_16x16x32_bf16(wh, hh, a0, 0, 0, 0);
        a1 = __builtin_amdgcn_mfma_f32_16x16x32_bf16(wh, hl, a1, 0, 0, 0);
        a2 = __builtin_amdgcn_mfma_f32_16x16x32_bf16(wl, hh, a2, 0, 0, 0);
      }
      v4f acc = a0 + a1 + a2;
      if (mt == 0){
        int col = nt*16 + fr;
        int r0w = (l >> 4)*4;
        #pragma unroll
        for (int q2=0;q2<4;q2++) gv2[r0w + q2][col] = acc[q2];
      } else if ((l >> 4) == 0){
        int b = nt*16 + fr;
        float* dg = dec_g + (size_t)par*B_*A_ + (size_t)b*A_ + beta*4;
        unsigned long long p0 = ((unsigned long long)__float_as_uint(acc[1]) << 32) | __float_as_uint(acc[0]);
        unsigned long long p1 = ((unsigned long long)__float_as_uint(acc[3]) << 32) | __float_as_uint(acc[2]);
        AST(reinterpret_cast<unsigned long long*>(dg), p0);
        AST(reinterpret_cast<unsigned long long*>(dg + 2), p1);
      }
    }
    ldsbar();

    // ---- LSTM pointwise + publish h ----
    if (i < T_ && tid < 128){
      int hh = tid >> 5;
      int hidx = beta*4 + hh;
      const float* Gr = G2 + (size_t)i*65536 + (size_t)hidx*32 + b32;
      float gi = gv2[0*4+hh][b32] + Gr[0];
      float gf = gv2[1*4+hh][b32] + Gr[16384];
      float gz = gv2[2*4+hh][b32] + Gr[32768];
      float go = gv2[3*4+hh][b32] + Gr[49152];
      float co = c_l[tid];
      float cn = fsig(gf)*co + fsig(gi)*ftanh(gz);
      float hn = fsig(go)*ftanh(cn);
      c_l[tid] = cn;
      AST(h_gT + (size_t)(par^1)*16384 + (size_t)hidx*32 + b32, hn);
      catbuf[(size_t)(b32*T_ + i)*H3_ + H2_ + hidx] = hn;
    }
    gridbar2(bar, ++gen, grp);

    // ---- prefetch h_{i+1} (overlaps Y) ----
    if (i < T_){
      const unsigned long long* hp =
        reinterpret_cast<const unsigned long long*>(h_gT + (size_t)(par^1)*16384);
      #pragma unroll
      for (int kk=0;kk<8;kk++)
        hld[kk] = ALD(hp + (size_t)(kg*8 + kk)*16 + (b2 >> 1));
    }

    // ---- finish step i-2 (mz published iter i-1, ordered by gridbar) ----
    if (i >= 2){
      if (tid < 4){
        unsigned long long v = ALD(mz + (size_t)(i & 1)*128 + bb*4 + tid);
        smz[tid][0] = __uint_as_float((unsigned)v);
        smz[tid][1] = __uint_as_float((unsigned)(v >> 32));
      }
      __syncthreads();
      float gm = fmaxf(fmaxf(smz[0][0], smz[1][0]), fmaxf(smz[2][0], smz[3][0]));
      float gZ = smz[0][1]*__expf(smz[0][0]-gm) + smz[1][1]*__expf(smz[1][0]-gm)
               + smz[2][1]*__expf(smz[2][0]-gm) + smz[3][1]*__expf(smz[3][0]-gm);
      float invZ = 1.f/gZ;
      int r2 = bb*T_ + (i-2);
      if (tid < 100){
        float av = __expf(sc_l[tid] - gm)*invZ;
        int s = sq*100 + tid;
        float cn = cov_l[tid] + av;
        cov_l[tid] = cn;
        attns[(size_t)r2*S_ + s] = av;
        covs[(size_t)r2*S_ + s]  = cn;
      }
      __syncthreads();
    }

    // ---- scores step i-1; publish (m,Z) to mz[(i-1)&1] ----
    if (i >= 1 && i <= T_){
      if (tid < 512) dec_l[tid] = ALD(dec_g + (size_t)par*B_*A_ + (size_t)bb*A_ + tid);
      ldsbar();
      int a0i = l*8;
      float dec8[8];
      #pragma unroll
      for (int j=0;j<8;j++) dec8[j] = dec_l[a0i+j];
      #pragma unroll
      for (int it=0; it<7; ++it){
        int sl = w + it*16;
        if (sl < 100){
          int s = sq*100 + sl;
          float cv = cov_l[sl];
          uint4 e8 = *reinterpret_cast<const uint4*>(ep_bf + (size_t)(bb*S_ + s)*A_ + a0i);
          unsigned uu[4] = {e8.x, e8.y, e8.z, e8.w};
          float part = 0.f;
          #pragma unroll
          for (int j=0;j<4;j++){
            float xa = bf2f((u16)(uu[j] & 0xFFFFu)) + dec8[2*j]   + cv*wc8[2*j];
            part += va8[2*j]*ftanh(xa);
            float xb = bf2f((u16)(uu[j] >> 16))     + dec8[2*j+1] + cv*wc8[2*j+1];
            part += va8[2*j+1]*ftanh(xb);
          }
          part = wsum(part);
          if (l == 0){
            bool on = bytemode ? (m8p[bb*S_+s] != 0) : (m32p[bb*S_+s] != 0u);
            sc_l[sl] = on ? part : -1e9f;
          }
        }
      }
      __syncthreads();
      if (tid < 64){
        float x1v = sc_l[l];
        float x2v = (l + 64 < 100) ? sc_l[l + 64] : -1e30f;
        float m = wmax(fmaxf(x1v, x2v));
        float z = __expf(x1v - m) + ((l + 64 < 100) ? __expf(x2v - m) : 0.f);
        z = wsum(z);
        if (l == 0){
          unsigned long long pk = ((unsigned long long)__float_as_uint(z) << 32)
                                | (unsigned long long)__float_as_uint(m);
          AST(mz + (size_t)((i-1) & 1)*128 + bb*4 + sq, pk);
        }
      }
    }

    // ---- unpack prefetched h for next iteration ----
    if (i < T_){
      #pragma unroll
      for (int kk=0;kk<8;kk++){
        hA[kk] = __uint_as_float((unsigned)hld[kk]);
        hB[kk] = __uint_as_float((unsigned)(hld[kk] >> 32));
      }
    }
  }
}

// ---------------- post-loop kernels ----------------

// context (deferred): catbuf[:, :1024] = attns @ enc_hi(bf16)  (single pass)
__global__ __launch_bounds__(256, 2) void k_ctx(
  const float* __restrict__ attns, const u16* __restrict__ enc3, float* __restrict__ catbuf)
{
  __shared__ float att_s[32][400];
  int d0 = blockIdx.x*64, b = blockIdx.y;
  int tid = threadIdx.x;
  for (int tt=0; tt<32; ++tt)
    for (int s = tid; s < S_; s += 256)
      att_s[tt][s] = attns[(size_t)(b*T_ + tt)*S_ + s];
  __syncthreads();
  int lane = tid & 31;
  int d = d0 + lane*2;
  int tg = tid >> 5;                 // 8 groups x 4 t
  float acc0[4] = {0,0,0,0}, acc1[4] = {0,0,0,0};
  const u16* encb = enc3 + (size_t)(b*S_)*3072 + d;
  #pragma unroll 4
  for (int s=0; s<S_; ++s){
    unsigned uv = *reinterpret_cast<const unsigned*>(encb + (size_t)s*3072);
    float e0 = bf2f((u16)(uv & 0xFFFFu));
    float e1 = bf2f((u16)(uv >> 16));
    #pragma unroll
    for (int i=0;i<4;i++){
      float av = att_s[tg*4 + i][s];
      acc0[i] = __builtin_fmaf(av, e0, acc0[i]);
      acc1[i] = __builtin_fmaf(av, e1, acc1[i]);
    }
  }
  #pragma unroll
  for (int i=0;i<4;i++)
    *reinterpret_cast<float2*>(catbuf + (size_t)(b*T_ + tg*4 + i)*H3_ + d) =
      make_float2(acc0[i], acc1[i]);
}

// fp32 tiled GEMM: dec_states = tanh(catbuf @ W_ah + b_ah); optional bf16 copy
__global__ __launch_bounds__(256) void k_ahgemm(
  const float* __restrict__ Acat, const float* __restrict__ W_ah, const float* __restrict__ b_ah,
  float* __restrict__ dec_states, u16* __restrict__ ah_bf)
{
  __shared__ float Asf[32][68];
  __shared__ float Bsf[32][64];
  int n0 = blockIdx.x*64, m0 = blockIdx.y*64;
  int tid = threadIdx.x;
  int tx = tid & 15, ty = tid >> 4;
  float acc[4][4] = {};
  for (int kc = 0; kc < H3_; kc += 32){
    __syncthreads();
    #pragma unroll
    for (int i=0;i<8;i++){
      int e = i*256 + tid;
      Asf[e & 31][e >> 5] = Acat[(size_t)(m0 + (e >> 5))*H3_ + kc + (e & 31)];
    }
    #pragma unroll
    for (int i=0;i<8;i++){
      int e = i*256 + tid;
      Bsf[e >> 6][e & 63] = W_ah[(size_t)(kc + (e >> 6))*H_ + n0 + (e & 63)];
    }
    __syncthreads();
    #pragma unroll
    for (int k=0;k<32;k++){
      float4 a4 = *reinterpret_cast<const float4*>(&Asf[k][ty*4]);
      float4 b4 = *reinterpret_cast<const float4*>(&Bsf[k][tx*4]);
      float av[4] = {a4.x, a4.y, a4.z, a4.w};
      float bv[4] = {b4.x, b4.y, b4.z, b4.w};
      #pragma unroll
      for (int i=0;i<4;i++)
        #pragma unroll
        for (int j=0;j<4;j++)
          acc[i][j] = __builtin_fmaf(av[i], bv[j], acc[i][j]);
    }
  }
  #pragma unroll
  for (int i=0;i<4;i++){
    int rr = m0 + ty*4 + i;
    #pragma unroll
    for (int j=0;j<4;j++){
      int cc = n0 + tx*4 + j;
      float v = ftanh(acc[i][j] + b_ah[cc]);
      dec_states[(size_t)rr*H_ + cc] = v;
      if (ah_bf) ah_bf[(size_t)rr*H_ + cc] = f2bf(v);
    }
  }
}

__global__ __launch_bounds__(512) void k_pgen(const float* __restrict__ catbuf, const float* __restrict__ emb,
  const float* __restrict__ W_pg, const float* __restrict__ b_pg, float* __restrict__ pgens)
{
  int w = threadIdx.x >> 6, l = threadIdx.x & 63;
  int r = blockIdx.x*8 + w;
  float part = 0.0f;
  for (int d = l; d < PGK_; d += 64){
    float x = (d < H3_) ? catbuf[(size_t)r*H3_ + d] : emb[(size_t)r*E_ + (d - H3_)];
    part += x*W_pg[d];
  }
  part = wsum(part);
  if (l == 0) pgens[r] = fsig(part + b_pg[0]);
}

// per-row final: stats merge -> bitmask+hash scatter -> fast log transform
// rowbf != nullptr: logits were written bf16 to d_ws (saves 205 MB HBM)
__global__ __launch_bounds__(512) void k_final2(
  float* __restrict__ logits, const u16* __restrict__ rowbf,
  const float* __restrict__ pgens,
  const float* __restrict__ attns, const int* __restrict__ src,
  const float2* __restrict__ stats, int nblk)
{
  __shared__ unsigned bits[1568];
  __shared__ unsigned keys[1024];
  __shared__ float vals[1024];
  __shared__ float sred[18];
  int r = blockIdx.x;
  int b = r >> 5;
  int tid = threadIdx.x;
  int w = tid >> 6, l = tid & 63;
  float* row = logits + (size_t)r*V_;
  const u16* rb = rowbf ? (rowbf + (size_t)r*V_) : nullptr;

  for (int i = tid; i < 1568; i += 512) bits[i] = 0u;
  for (int i = tid; i < 1024; i += 512){ keys[i] = 0xFFFFFFFFu; vals[i] = 0.0f; }

  if (stats){
    float m = -1e30f, Z = 0.0f;
    if (tid < nblk){ float2 st = stats[(size_t)r*nblk + tid]; m = st.x; Z = st.y; }
    #pragma unroll
    for (int off=32; off>0; off>>=1){
      float mo = __shfl_xor(m, off, 64);
      float Zo = __shfl_xor(Z, off, 64);
      float nm = fmaxf(m, mo);
      Z = Z*__expf(m - nm) + Zo*__expf(mo - nm);
      m = nm;
    }
    if (l == 0){ sred[w*2] = m; sred[w*2+1] = Z; }
    __syncthreads();
    if (tid == 0){
      float gm = -1e30f, gz = 0.0f;
      #pragma unroll
      for (int i=0;i<8;i++){
        float mi = sred[i*2], zi = sred[i*2+1];
        float nm = fmaxf(gm, mi);
        gz = gz*__expf(gm - nm) + zi*__expf(mi - nm);
        gm = nm;
      }
      sred[16] = gm; sred[17] = gz;
    }
    __syncthreads();
  } else {
    float m = -1e30f;
    for (int j = tid; j < V_/4; j += 512){
      float4 x = reinterpret_cast<const float4*>(row)[j];
      m = fmaxf(fmaxf(m, x.x), fmaxf(fmaxf(x.y, x.z), x.w));
    }
    m = wmax(m);
    if (l == 0) sred[w] = m;
    __syncthreads();
    if (tid == 0){
      float gm = -1e30f;
      #pragma unroll
      for (int i=0;i<8;i++) gm = fmaxf(gm, sred[i]);
      sred[16] = gm;
    }
    __syncthreads();
    float gm = sred[16];
    float z = 0.0f;
    for (int j = tid; j < V_/4; j += 512){
      float4 x = reinterpret_cast<const float4*>(row)[j];
      z += __expf(x.x-gm) + __expf(x.y-gm) + __expf(x.z-gm) + __expf(x.w-gm);
    }
    z = wsum(z);
    if (l == 0) sred[8 + w] = z;
    __syncthreads();
    if (tid == 0){
      float gz = 0.0f;
      #pragma unroll
      for (int i=0;i<8;i++) gz += sred[8 + i];
      sred[17] = gz;
    }
    __syncthreads();
  }

  float gm = sred[16];
  float gZ = sred[17];
  float pg = pgens[r];
  float scale = pg / gZ;
  float lscale = __logf(scale);

  if (tid < S_){
    int tok = src[b*S_ + tid];
    float add = (1.0f - pg)*attns[(size_t)r*S_ + tid];
    atomicOr(&bits[tok >> 5], 1u << (tok & 31));
    unsigned h = ((unsigned)tok * 2654435761u) >> 22;
    while (true){
      unsigned prev = atomicCAS(&keys[h], 0xFFFFFFFFu, (unsigned)tok);
      if (prev == 0xFFFFFFFFu || prev == (unsigned)tok){
        atomicAdd(&vals[h], add);
        break;
      }
      h = (h + 1) & 1023;
    }
  }
  __syncthreads();

  for (int j = tid; j < V_/4; j += 512){
    float xv[4];
    if (rb){
      uint2 u = reinterpret_cast<const uint2*>(rb)[j];
      xv[0] = bf2f((u16)(u.x & 0xFFFFu)); xv[1] = bf2f((u16)(u.x >> 16));
      xv[2] = bf2f((u16)(u.y & 0xFFFFu)); xv[3] = bf2f((u16)(u.y >> 16));
    } else {
      float4 x = reinterpret_cast<const float4*>(row)[j];
      xv[0] = x.x; xv[1] = x.y; xv[2] = x.z; xv[3] = x.w;
    }
    int v = 4*j;
    float o[4];
    #pragma unroll
    for (int k=0;k<4;k++){
      int vv = v + k;
      bool hit = (bits[vv >> 5] >> (vv & 31)) & 1u;
      float tt = xv[k] - gm + lscale;
      if (!hit && tt > -25.0f){
        o[k] = tt;
      } else {
        float pval = __expf(xv[k] - gm)*scale;
        if (hit){
          unsigned h = ((unsigned)vv * 2654435761u) >> 22;
          while (keys[h] != 0xFFFFFFFFu){
            if (keys[h] == (unsigned)vv){ pval += vals[h]; break; }
            h = (h + 1) & 1023;
          }
        }
        o[k] = __logf(pval + 1e-20f);
      }
    }
    reinterpret_cast<float4*>(row)[j] = make_float4(o[0], o[1], o[2], o[3]);
  }
}

// ---------------- host ----------------

extern "C" void kernel_launch(void* const* d_in, const int* in_sizes, int n_in,
                              void* d_out, int out_size, void* d_ws, size_t ws_size,
                              hipStream_t stream)
{
  const int* src_tokens = (const int*)d_in[0];
  const float* embedded = (const float*)d_in[1];
  const float* enc      = (const float*)d_in[2];
  const void*  maskp    = (const void*)d_in[3];
  const float* h0  = (const float*)d_in[4];
  const float* c0  = (const float*)d_in[5];
  const float* W_ih = (const float*)d_in[6];
  const float* W_hh = (const float*)d_in[7];
  const float* b_ih = (const float*)d_in[8];
  const float* b_hh = (const float*)d_in[9];
  const float* W_enc = (const float*)d_in[10];
  const float* W_dec = (const float*)d_in[11];
  const float* w_cov = (const float*)d_in[12];
  const float* b_att = (const float*)d_in[13];
  const float* v_att = (const float*)d_in[14];
  const float* W_ah  = (const float*)d_in[15];
  const float* b_ah  = (const float*)d_in[16];
  const float* W_pg  = (const float*)d_in[17];
  const float* b_pg  = (const float*)d_in[18];
  const float* W_v   = (const float*)d_in[19];
  const float* b_v   = (const float*)d_in[20];
  (void)in_sizes; (void)n_in; (void)out_size;

  float* outp = (float*)d_out;
  float* logps = outp;                                  // (B,T,V)   204.8 MB
  float* dec_states = logps + (size_t)R_*V_;            // (B,T,H)
  float* attns = dec_states + (size_t)R_*H_;            // (B,T,S)
  float* covs  = attns + (size_t)R_*S_;                 // (B,T,S)
  float* pgens = covs + (size_t)R_*S_;                  // (B,T)

  // big transients live INSIDE the logps output region (dead until W_v GEMM)
  char* sp = (char*)logps;
  auto salloc = [&](size_t bytes) -> void* {
    void* p = (void*)sp;
    sp += (bytes + 255) & ~(size_t)255;
    return p;
  };
  unsigned* bar = (unsigned*)salloc(2048);
  unsigned long long* mz = (unsigned long long*)salloc((size_t)2*B_*4*8);
  u16* ep_bf    = (u16*)salloc((size_t)B_*S_*A_*2);        // 13.1 MB
  u16* enc3     = (u16*)salloc((size_t)B_*S_*3072*2);      // 78.6 MB
  u16* WencT3   = (u16*)salloc((size_t)A_*3072*2);         // 3.1 MB
  float* G2     = (float*)salloc((size_t)R_*H4_*4);        // 8.4 MB [t][g][hidx][b]
  float* catbuf = (float*)salloc((size_t)R_*H3_*4);        // 6.3 MB [context | h]
  float* dec_g  = (float*)salloc((size_t)2*B_*A_*4);       // 128 KB double-buffered
  float* h_gT   = (float*)salloc((size_t)2*H_*B_*4);       // 128 KB double-buffered [k][b]
  // total ~110 MB < 204.8 MB -- all consumed before W_v GEMM writes logps

  // d_ws: only buffers live WHILE logps is being written
  char* wp = (char*)d_ws;
  auto walloc = [&](size_t bytes) -> void* {
    void* p = (void*)wp;
    wp += (bytes + 255) & ~(size_t)255;
    return p;
  };
  u16* ah_bf = (u16*)walloc((size_t)R_*H_*2);              // 1.05 MB
  u16* WvT   = (u16*)walloc((size_t)V_*H_*2);              // 51.2 MB
  float2* stats = (float2*)walloc((size_t)R_*NBLKV_*8);    // 3.2 MB
  u16* logits_bf = (u16*)walloc((size_t)R_*V_*2);          // 102.4 MB (optional tier)
  const size_t ws_fast  = (size_t)R_*H_*2 + (size_t)V_*H_*2 + 512;
  const size_t ws_stats = ws_fast + (size_t)R_*NBLKV_*8 + 256;
  const size_t ws_bf    = ws_stats + (size_t)R_*V_*2 + 256;
  const bool fast_wv   = (ws_size >= ws_fast);
  const bool use_stats = (ws_size >= ws_stats);
  const bool use_bf    = (ws_size >= ws_bf) && use_stats;

  // setup
  k_init0<<<1, 512, 0, stream>>>(bar, mz);
  k_gih<<<128, 256, 0, stream>>>(embedded, W_ih, b_ih, b_hh, G2);
  k_conv3<<<(B_*S_*H2_/4 + 255)/256, 256, 0, stream>>>(enc, enc3, B_*S_*H2_/4);
  k_convT3<<<dim3(8,16), 256, 0, stream>>>(W_enc, WencT3);

  // enc_proj: single split-bf16 GEMM (K=3072), bf16 output + b_att
  k_gemm_bf16<<<dim3(A_/128, (B_*S_)/128), 256, 0, stream>>>(
      enc3, 3072, WencT3, 3072, b_att, nullptr, ep_bf, A_, B_*S_, A_, 3072, nullptr, 0);

  // fused persistent recurrence + co-scheduled WvT transpose on idle CUs
  k_recur<<<GRBX_, 1024, 0, stream>>>(W_hh, G2, W_dec, ep_bf, w_cov, v_att, maskp,
                                      h0, c0, h_gT, dec_g, mz,
                                      catbuf, attns, covs, bar,
                                      W_v, fast_wv ? WvT : (u16*)nullptr);

  // deferred contexts + batched tail
  k_ctx<<<dim3(16, 32), 256, 0, stream>>>(attns, enc3, catbuf);
  k_ahgemm<<<dim3(8,16), 256, 0, stream>>>(catbuf, W_ah, b_ah, dec_states, fast_wv ? ah_bf : (u16*)nullptr);
  k_pgen<<<128, 512, 0, stream>>>(catbuf, embedded, W_pg, b_pg, pgens);

  // logits
  if (fast_wv)
    k_gemm_bf16<<<dim3(NBLKV_, R_/128), 256, 0, stream>>>(
        ah_bf, H_, WvT, H_, b_v,
        use_bf ? nullptr : logps, use_bf ? logits_bf : nullptr, V_,
        R_, V_, H_, use_stats ? stats : nullptr, NBLKV_);
  else
    k_wv_f32<<<dim3((V_+63)/64, R_/64), 256, 0, stream>>>(dec_states, W_v, b_v, logps);

  k_final2<<<R_, 512, 0, stream>>>(logps, use_bf ? logits_bf : (u16*)nullptr,
                                   pgens, attns, src_tokens,
                                   (fast_wv && use_stats) ? stats : nullptr, NBLKV_);
}